// Round 1
// baseline (34965.070 us; speedup 1.0000x reference)
//
#include <hip/hip_runtime.h>
#include <hip/hip_bf16.h>

// Bidirectional 2-layer LSTM, persistent single-kernel implementation.
// I=256, H=512, L=2, D=2, O=8, B=64, S=512.
//
// Strategy:
//  - One persistent kernel, 256 WGs x 256 threads, custom device-scope
//    atomic barriers (all WGs co-resident: VGPR capped at 256 -> >=2 WGs/CU
//    capacity, grid=256 <= 256 CUs).
//  - All matmuls in bf16 MFMA 16x16x32, fp32 accumulate. c-state fp32 in regs.
//  - Gate columns permuted: perm row 4*u+g = orig row g*512+u, so one wave
//    owns 4 complete hidden units (16 gate cols) x 16 batch rows.
//  - Recurrent weights live in VGPRs across all 512 steps (24/48 frags).
//  - Input contribution folded into step GEMM (K = [h | x]).
//  - y0[t] slabs double as the h broadcast buffers (no extra sync hazards).

typedef __attribute__((ext_vector_type(8))) __bf16 bf16x8;
typedef __attribute__((ext_vector_type(4))) float f32x4;

struct Params {
  const float *input_seq, *h0, *c0;
  const float *w_ih_0f, *w_hh_0f, *b_0f;
  const float *w_ih_0b, *w_hh_0b, *b_0b;
  const float *w_ih_1f, *w_hh_1f, *b_1f;
  const float *w_ih_1b, *w_hh_1b, *b_1b;
  const float *fc_w, *fc_b;
  float* out;
  unsigned* cnt;          // barrier counters (zeroed via hipMemsetAsync)
  __bf16* xT;             // [512][64][256]  time-major bf16 input
  __bf16* Wp0f; __bf16* Wp0b;   // [2048 perm rows][768 = 512 hh | 256 ih]
  __bf16* Wp1f; __bf16* Wp1b;   // [2048 perm rows][1536 = 512 hh | 1024 ih]
  __bf16* y0;             // [514][64][1024]; slab s = t+1; slab0/513 = inits
  __bf16* h1buf;          // [3][64][512]; slabs 0/1 ping-pong, 2 = init
  __bf16* h1binit;        // [64][512]
  __bf16* h1bout;         // [64][512]
  float* bp;              // [4][2048] permuted biases (0f,0b,1f,1b)
};

__device__ __forceinline__ float sigm(float x) { return 1.f / (1.f + __expf(-x)); }

// Inter-workgroup barrier: monotonic counter, device(agent)-scope semantics.
// Release on add publishes this WG's global stores (L2 writeback), acquire on
// the spin load invalidates stale L1/L2 before the next step's h reads.
__device__ __forceinline__ void wg_barrier(unsigned* cnt, unsigned target) {
  __syncthreads();                       // drains vmcnt: all h stores issued to L2
  if (threadIdx.x == 0) {
    __threadfence();
    __hip_atomic_fetch_add(cnt, 1u, __ATOMIC_RELEASE, __HIP_MEMORY_SCOPE_AGENT);
    unsigned v;
    do {
      __builtin_amdgcn_s_sleep(1);
      v = __hip_atomic_load(cnt, __ATOMIC_ACQUIRE, __HIP_MEMORY_SCOPE_AGENT);
    } while (v < target);
    __threadfence();
  }
  __syncthreads();
}

__global__ __launch_bounds__(256, 2) void lstm_kernel(Params p) {
  const int tid  = threadIdx.x;
  const int wg   = blockIdx.x;
  const unsigned gtid = wg * 256 + tid;
  const int lane = tid & 63;
  const int wv   = tid >> 6;          // wave 0..3
  const int colq = lane & 15;         // tile col (B-operand n) / tile row (A-operand m)
  const int quad = lane >> 4;         // k-subblock selector
  const int bl   = lane >> 2;         // pointwise: local batch 0..15
  const int ul   = lane & 3;          // pointwise: local unit 0..3

  __shared__ float lds[4][256];
  float* ldsw = lds[wv];

  // ---------------- prologue: pack/permute/convert ----------------
  { // xT[t][b][:] = bf16(input_seq[b][t][:]); 65536 tasks of 128 elems
    int row = gtid >> 1, half = gtid & 1;
    int t = row >> 6, b = row & 63;
    const float* src = p.input_seq + ((size_t)b * 512 + t) * 256 + half * 128;
    __bf16* dst = p.xT + (size_t)row * 256 + half * 128;
    for (int i = 0; i < 128; i += 8) {
      bf16x8 v;
      #pragma unroll
      for (int j = 0; j < 8; ++j) v[j] = (__bf16)src[i + j];
      *(bf16x8*)(dst + i) = v;
    }
  }
  // Wp0{f,b}: [2048][768]; perm row rr: u=rr>>2,g=rr&3, orig row R=g*512+u
  for (unsigned task = gtid; task < 2u * 2048 * 6; task += 65536) {
    unsigned dir = task / (2048 * 6);
    unsigned rr = (task / 6) % 2048;
    unsigned ch = task % 6;
    unsigned R = (rr & 3) * 512 + (rr >> 2);
    const float* wih = dir ? p.w_ih_0b : p.w_ih_0f;
    const float* whh = dir ? p.w_hh_0b : p.w_hh_0f;
    __bf16* dst = (dir ? p.Wp0b : p.Wp0f) + (size_t)rr * 768;
    const float* src; unsigned kd;
    if (ch < 4) { src = whh + (size_t)R * 512 + ch * 128;        kd = ch * 128; }
    else        { src = wih + (size_t)R * 256 + (ch - 4) * 128;  kd = 512 + (ch - 4) * 128; }
    for (int i = 0; i < 128; i += 8) {
      bf16x8 v;
      #pragma unroll
      for (int j = 0; j < 8; ++j) v[j] = (__bf16)src[i + j];
      *(bf16x8*)(dst + kd + i) = v;
    }
  }
  // Wp1{f,b}: [2048][1536]
  for (unsigned task = gtid; task < 2u * 2048 * 12; task += 65536) {
    unsigned dir = task / (2048 * 12);
    unsigned rr = (task / 12) % 2048;
    unsigned ch = task % 12;
    unsigned R = (rr & 3) * 512 + (rr >> 2);
    const float* wih = dir ? p.w_ih_1b : p.w_ih_1f;
    const float* whh = dir ? p.w_hh_1b : p.w_hh_1f;
    __bf16* dst = (dir ? p.Wp1b : p.Wp1f) + (size_t)rr * 1536;
    const float* src; unsigned kd;
    if (ch < 4) { src = whh + (size_t)R * 512 + ch * 128;         kd = ch * 128; }
    else        { src = wih + (size_t)R * 1024 + (ch - 4) * 128;  kd = 512 + (ch - 4) * 128; }
    for (int i = 0; i < 128; i += 8) {
      bf16x8 v;
      #pragma unroll
      for (int j = 0; j < 8; ++j) v[j] = (__bf16)src[i + j];
      *(bf16x8*)(dst + kd + i) = v;
    }
  }
  // permuted biases
  if (gtid < 4u * 2048) {
    unsigned arr = gtid >> 11, rr = gtid & 2047;
    unsigned R = (rr & 3) * 512 + (rr >> 2);
    const float* src = arr == 0 ? p.b_0f : arr == 1 ? p.b_0b : arr == 2 ? p.b_1f : p.b_1b;
    p.bp[arr * 2048 + rr] = src[R];
  }
  // h inits (bf16): y0 slab0 cols[0:512)=h0[0]; slab513 cols[512:1024)=h0[1];
  // h1buf slab2=h0[2]; h1binit=h0[3]
  if (gtid < 4u * 4096) {
    unsigned dl = gtid >> 12;
    unsigned e = (gtid & 4095) * 8;
    unsigned b = e >> 9, u = e & 511;
    const float* src = p.h0 + (size_t)dl * 64 * 512 + (size_t)b * 512 + u;
    __bf16* dst;
    if (dl == 0)      dst = p.y0 + ((size_t)0 * 64 + b) * 1024 + u;
    else if (dl == 1) dst = p.y0 + ((size_t)513 * 64 + b) * 1024 + 512 + u;
    else if (dl == 2) dst = p.h1buf + ((size_t)2 * 64 + b) * 512 + u;
    else              dst = p.h1binit + (size_t)b * 512 + u;
    bf16x8 v;
    #pragma unroll
    for (int j = 0; j < 8; ++j) v[j] = (__bf16)src[j];
    *(bf16x8*)dst = v;
  }

  unsigned grid_tgt = 256;
  wg_barrier(p.cnt + 0, grid_tgt);

  // ---------------- P1: layer0 recurrence (both dirs concurrently) ----------------
  {
    const bool fwd = wg < 128;
    const int wgd = wg & 127;
    const int bg = wgd >> 5;             // 4 batch groups of 16
    const int ug = wgd & 31;             // 32 unit groups of 16
    const int bbase = bg * 16;
    const int uglob = ug * 16 + wv * 4;  // this wave: 4 hidden units
    const int colbase = uglob * 4;       // 16 permuted gate cols
    const __bf16* Wp = fwd ? p.Wp0f : p.Wp0b;
    bf16x8 wf[24];                       // register-resident weights (96 VGPRs)
    #pragma unroll
    for (int kb = 0; kb < 24; ++kb)
      wf[kb] = *(const bf16x8*)(Wp + (size_t)(colbase + colq) * 768 + kb * 32 + quad * 8);
    const float bias_col = p.bp[(fwd ? 0 : 1) * 2048 + colbase + colq];
    float c = p.c0[(size_t)(fwd ? 0 : 1) * 64 * 512 + (size_t)(bbase + bl) * 512 + uglob + ul];
    const int dcol = fwd ? 0 : 512;
    unsigned* cnt = p.cnt + (fwd ? 1 : 2);
    unsigned tgt = 0;
    for (int s = 0; s < 512; ++s) {
      const int t = fwd ? s : 511 - s;
      const int slabA = fwd ? t : t + 2;   // h(t-1) at slab t; h(t+1) at slab t+2
      const __bf16* aH = p.y0 + ((size_t)slabA * 64 + bbase + colq) * 1024 + dcol + quad * 8;
      const __bf16* aX = p.xT + ((size_t)t * 64 + bbase + colq) * 256 + quad * 8;
      f32x4 acc = {0.f, 0.f, 0.f, 0.f};
      #pragma unroll
      for (int kb = 0; kb < 16; ++kb)
        acc = __builtin_amdgcn_mfma_f32_16x16x32_bf16(*(const bf16x8*)(aH + kb * 32), wf[kb], acc, 0, 0, 0);
      #pragma unroll
      for (int kb = 0; kb < 8; ++kb)
        acc = __builtin_amdgcn_mfma_f32_16x16x32_bf16(*(const bf16x8*)(aX + kb * 32), wf[16 + kb], acc, 0, 0, 0);
      #pragma unroll
      for (int r = 0; r < 4; ++r) ldsw[(quad * 4 + r) * 16 + colq] = acc[r] + bias_col;
      __syncthreads();
      float gi = ldsw[bl * 16 + ul * 4 + 0];
      float gf = ldsw[bl * 16 + ul * 4 + 1];
      float gg = ldsw[bl * 16 + ul * 4 + 2];
      float go = ldsw[bl * 16 + ul * 4 + 3];
      c = sigm(gf) * c + sigm(gi) * tanhf(gg);
      float h = sigm(go) * tanhf(c);
      p.y0[((size_t)(t + 1) * 64 + bbase + bl) * 1024 + dcol + uglob + ul] = (__bf16)h;
      tgt += 128;
      wg_barrier(cnt, tgt);
    }
  }
  grid_tgt += 256;
  wg_barrier(p.cnt + 0, grid_tgt);

  // ---------------- P3: layer1 fwd (WGs 0-127) | P4: layer1 bwd single step (WGs 128-255) ----------------
  if (wg < 128) {
    const int bg = wg >> 5, ug = wg & 31;
    const int bbase = bg * 16;
    const int uglob = ug * 16 + wv * 4;
    const int colbase = uglob * 4;
    bf16x8 wf[48];                       // 192 VGPRs: [hh 16 | ih 32] frags
    #pragma unroll
    for (int kb = 0; kb < 48; ++kb)
      wf[kb] = *(const bf16x8*)(p.Wp1f + (size_t)(colbase + colq) * 1536 + kb * 32 + quad * 8);
    const float bias_col = p.bp[2 * 2048 + colbase + colq];
    float c = p.c0[(size_t)2 * 64 * 512 + (size_t)(bbase + bl) * 512 + uglob + ul];
    unsigned tgt = 0;
    for (int t = 0; t < 512; ++t) {
      const int prev = (t == 0) ? 2 : ((t - 1) & 1);
      const int cur = t & 1;
      const __bf16* aH = p.h1buf + ((size_t)prev * 64 + bbase + colq) * 512 + quad * 8;
      const __bf16* aX = p.y0 + ((size_t)(t + 1) * 64 + bbase + colq) * 1024 + quad * 8;
      f32x4 acc = {0.f, 0.f, 0.f, 0.f};
      #pragma unroll
      for (int kb = 0; kb < 16; ++kb)
        acc = __builtin_amdgcn_mfma_f32_16x16x32_bf16(*(const bf16x8*)(aH + kb * 32), wf[kb], acc, 0, 0, 0);
      #pragma unroll
      for (int kb = 0; kb < 32; ++kb)
        acc = __builtin_amdgcn_mfma_f32_16x16x32_bf16(*(const bf16x8*)(aX + kb * 32), wf[16 + kb], acc, 0, 0, 0);
      #pragma unroll
      for (int r = 0; r < 4; ++r) ldsw[(quad * 4 + r) * 16 + colq] = acc[r] + bias_col;
      __syncthreads();
      float gi = ldsw[bl * 16 + ul * 4 + 0];
      float gf = ldsw[bl * 16 + ul * 4 + 1];
      float gg = ldsw[bl * 16 + ul * 4 + 2];
      float go = ldsw[bl * 16 + ul * 4 + 3];
      c = sigm(gf) * c + sigm(gi) * tanhf(gg);
      float h = sigm(go) * tanhf(c);
      p.h1buf[((size_t)cur * 64 + bbase + bl) * 512 + uglob + ul] = (__bf16)h;
      tgt += 128;
      wg_barrier(p.cnt + 3, tgt);
    }
  } else {
    const int wgd = wg - 128;
    const int bg = wgd >> 5, ug = wgd & 31;
    const int bbase = bg * 16;
    const int uglob = ug * 16 + wv * 4;
    const int colbase = uglob * 4;
    const __bf16* aH = p.h1binit + (size_t)(bbase + colq) * 512 + quad * 8;
    const __bf16* aX = p.y0 + ((size_t)512 * 64 + bbase + colq) * 1024 + quad * 8;
    f32x4 acc = {0.f, 0.f, 0.f, 0.f};
    #pragma unroll
    for (int kb = 0; kb < 16; ++kb) {
      bf16x8 w = *(const bf16x8*)(p.Wp1b + (size_t)(colbase + colq) * 1536 + kb * 32 + quad * 8);
      acc = __builtin_amdgcn_mfma_f32_16x16x32_bf16(*(const bf16x8*)(aH + kb * 32), w, acc, 0, 0, 0);
    }
    #pragma unroll
    for (int kb = 0; kb < 32; ++kb) {
      bf16x8 w = *(const bf16x8*)(p.Wp1b + (size_t)(colbase + colq) * 1536 + (16 + kb) * 32 + quad * 8);
      acc = __builtin_amdgcn_mfma_f32_16x16x32_bf16(*(const bf16x8*)(aX + kb * 32), w, acc, 0, 0, 0);
    }
    const float bias_col = p.bp[3 * 2048 + colbase + colq];
    #pragma unroll
    for (int r = 0; r < 4; ++r) ldsw[(quad * 4 + r) * 16 + colq] = acc[r] + bias_col;
    __syncthreads();
    float gi = ldsw[bl * 16 + ul * 4 + 0];
    float gf = ldsw[bl * 16 + ul * 4 + 1];
    float gg = ldsw[bl * 16 + ul * 4 + 2];
    float go = ldsw[bl * 16 + ul * 4 + 3];
    float c = p.c0[(size_t)3 * 64 * 512 + (size_t)(bbase + bl) * 512 + uglob + ul];
    c = sigm(gf) * c + sigm(gi) * tanhf(gg);
    float h = sigm(go) * tanhf(c);
    p.h1bout[(size_t)(bbase + bl) * 512 + uglob + ul] = (__bf16)h;
  }
  grid_tgt += 256;
  wg_barrier(p.cnt + 0, grid_tgt);

  // ---------------- FC: out[b][o] = fc_b[o] + last[b,:] . fc_w[o,:] ----------------
  if (wg < 8) {
    const int b = wg * 8 + (tid >> 5);
    const int o = (tid >> 2) & 7;
    const int ks = tid & 3;
    const int k0 = ks * 256;
    const __bf16* l1 = p.h1buf + ((size_t)1 * 64 + b) * 512;   // h1f(t=511), slab 511&1=1
    const __bf16* l2 = p.h1bout + (size_t)b * 512;             // h1b(t=511)
    const __bf16* hsrc = (ks < 2) ? (l1 + k0) : (l2 + k0 - 512);
    const float* w = p.fc_w + (size_t)o * 1024 + k0;
    float acc = 0.f;
    for (int k = 0; k < 256; ++k) acc += (float)hsrc[k] * w[k];
    acc += __shfl_down(acc, 2, 4);
    acc += __shfl_down(acc, 1, 4);
    if (ks == 0) p.out[b * 8 + o] = acc + p.fc_b[o];
  }
}

extern "C" void kernel_launch(void* const* d_in, const int* in_sizes, int n_in,
                              void* d_out, int out_size, void* d_ws, size_t ws_size,
                              hipStream_t stream) {
  char* ws = (char*)d_ws;
  Params p;
  p.input_seq = (const float*)d_in[0];
  p.h0 = (const float*)d_in[1];
  p.c0 = (const float*)d_in[2];
  p.w_ih_0f = (const float*)d_in[3];  p.w_hh_0f = (const float*)d_in[4];  p.b_0f = (const float*)d_in[5];
  p.w_ih_0b = (const float*)d_in[6];  p.w_hh_0b = (const float*)d_in[7];  p.b_0b = (const float*)d_in[8];
  p.w_ih_1f = (const float*)d_in[9];  p.w_hh_1f = (const float*)d_in[10]; p.b_1f = (const float*)d_in[11];
  p.w_ih_1b = (const float*)d_in[12]; p.w_hh_1b = (const float*)d_in[13]; p.b_1b = (const float*)d_in[14];
  p.fc_w = (const float*)d_in[15];    p.fc_b = (const float*)d_in[16];
  p.out = (float*)d_out;

  size_t off = 0;
  p.cnt    = (unsigned*)(ws + off); off += 4096;
  p.xT     = (__bf16*)(ws + off);   off += (size_t)512 * 64 * 256 * 2;
  p.Wp0f   = (__bf16*)(ws + off);   off += (size_t)2048 * 768 * 2;
  p.Wp0b   = (__bf16*)(ws + off);   off += (size_t)2048 * 768 * 2;
  p.Wp1f   = (__bf16*)(ws + off);   off += (size_t)2048 * 1536 * 2;
  p.Wp1b   = (__bf16*)(ws + off);   off += (size_t)2048 * 1536 * 2;
  p.y0     = (__bf16*)(ws + off);   off += (size_t)514 * 64 * 1024 * 2;
  p.h1buf  = (__bf16*)(ws + off);   off += (size_t)3 * 64 * 512 * 2;
  p.h1binit= (__bf16*)(ws + off);   off += (size_t)64 * 512 * 2;
  p.h1bout = (__bf16*)(ws + off);   off += (size_t)64 * 512 * 2;
  p.bp     = (float*)(ws + off);    off += (size_t)4 * 2048 * 4;
  (void)ws_size; (void)in_sizes; (void)n_in; (void)out_size;

  hipMemsetAsync(d_ws, 0, 4096, stream);   // zero barrier counters (ws is re-poisoned each call)
  lstm_kernel<<<dim3(256), dim3(256), 0, stream>>>(p);
}

// Round 2
// 18423.476 us; speedup vs baseline: 1.8979x; 1.8979x over previous
//
#include <hip/hip_runtime.h>
#include <hip/hip_bf16.h>

// Bidirectional 2-layer LSTM, persistent single-kernel implementation.
// I=256, H=512, L=2, D=2, O=8, B=64, S=512.
//
// Round 2: replaced the single-counter atomic barrier (128 serialized RMWs
// ~= 32us/step, measured) with per-WG flag slots + parallel 32-lane polling,
// split into independent sync groups per (direction, batch-group), and
// XCD-local group mapping (group = wg & 7 -> all 32 WGs of a group land on
// one XCD under round-robin dispatch; correctness is agent-scope regardless).

typedef __attribute__((ext_vector_type(8))) __bf16 bf16x8;
typedef __attribute__((ext_vector_type(4))) float f32x4;

#define SLOT 32   // u32s per flag slot = 128 B (one L2 line), no false sharing

struct Params {
  const float *input_seq, *h0, *c0;
  const float *w_ih_0f, *w_hh_0f, *b_0f;
  const float *w_ih_0b, *w_hh_0b, *b_0b;
  const float *w_ih_1f, *w_hh_1f, *b_1f;
  const float *w_ih_1b, *w_hh_1b, *b_1b;
  const float *fc_w, *fc_b;
  float* out;
  unsigned* flags;        // [640 slots x 32 u32]: 0..255 phase, 256..511 L0(8x32), 512..639 L1(4x32)
  __bf16* xT;             // [512][64][256]  time-major bf16 input
  __bf16* Wp0f; __bf16* Wp0b;   // [2048 perm rows][768 = 512 hh | 256 ih]
  __bf16* Wp1f; __bf16* Wp1b;   // [2048 perm rows][1536 = 512 hh | 1024 ih]
  __bf16* y0;             // [514][64][1024]; slab s = t+1; slab0/513 = inits
  __bf16* h1buf;          // [3][64][512]; slabs 0/1 ping-pong, 2 = init
  __bf16* h1binit;        // [64][512]
  __bf16* h1bout;         // [64][512]
  float* bp;              // [4][2048] permuted biases (0f,0b,1f,1b)
};

__device__ __forceinline__ float sigm(float x) { return 1.f / (1.f + __expf(-x)); }

// Global phase barrier: each WG posts its slot (parallel stores), each thread
// polls one slot, collective exit via __syncthreads_and. No serialized RMWs.
__device__ __forceinline__ void phase_barrier(unsigned* slots, int wg, int tid, unsigned phase) {
  __syncthreads();
  if (tid == 0) {
    __builtin_amdgcn_fence(__ATOMIC_RELEASE, "agent");
    __hip_atomic_store(slots + (size_t)wg * SLOT, phase, __ATOMIC_RELAXED, __HIP_MEMORY_SCOPE_AGENT);
  }
  bool ok;
  do {
    unsigned v = __hip_atomic_load(slots + (size_t)tid * SLOT, __ATOMIC_RELAXED, __HIP_MEMORY_SCOPE_AGENT);
    ok = v >= phase;
    if (!ok) __builtin_amdgcn_s_sleep(4);
  } while (!__syncthreads_and(ok));
  __builtin_amdgcn_fence(__ATOMIC_ACQUIRE, "agent");
}

// Consumer side: wait until all 32 group flags >= need. 32 lanes poll 32 slots
// in parallel -> one memory round trip per iteration. Every wave polls
// independently (no intra-WG barrier needed before the reads).
__device__ __forceinline__ void group_wait(const unsigned* base, int lane, unsigned need) {
  bool ok;
  do {
    ok = true;
    if (lane < 32) {
      unsigned v = __hip_atomic_load(base + (size_t)lane * SLOT, __ATOMIC_RELAXED, __HIP_MEMORY_SCOPE_AGENT);
      ok = v >= need;
    }
    if (__ballot(ok) == ~0ull) break;
    __builtin_amdgcn_s_sleep(1);
  } while (true);
  __builtin_amdgcn_fence(__ATOMIC_ACQUIRE, "agent");
}

// Producer side: all threads' global stores drained by __syncthreads (vmcnt(0)
// before s_barrier), then one release fence (wbl2) + plain flag store.
__device__ __forceinline__ void group_post(unsigned* slot, int tid, unsigned val) {
  __syncthreads();
  if (tid == 0) {
    __builtin_amdgcn_fence(__ATOMIC_RELEASE, "agent");
    __hip_atomic_store(slot, val, __ATOMIC_RELAXED, __HIP_MEMORY_SCOPE_AGENT);
  }
}

__global__ __launch_bounds__(256, 2) void lstm_kernel(Params p) {
  const int tid  = threadIdx.x;
  const int wg   = blockIdx.x;
  const unsigned gtid = wg * 256 + tid;
  const int lane = tid & 63;
  const int wv   = tid >> 6;          // wave 0..3
  const int colq = lane & 15;         // tile col (B-operand n) / tile row (A-operand m)
  const int quad = lane >> 4;         // k-subblock selector
  const int bl   = lane >> 2;         // pointwise: local batch 0..15
  const int ul   = lane & 3;          // pointwise: local unit 0..3

  __shared__ float lds[4][256];
  float* ldsw = lds[wv];

  // ---------------- prologue: pack/permute/convert ----------------
  { // xT[t][b][:] = bf16(input_seq[b][t][:]); 65536 tasks of 128 elems
    int row = gtid >> 1, half = gtid & 1;
    int t = row >> 6, b = row & 63;
    const float* src = p.input_seq + ((size_t)b * 512 + t) * 256 + half * 128;
    __bf16* dst = p.xT + (size_t)row * 256 + half * 128;
    for (int i = 0; i < 128; i += 8) {
      bf16x8 v;
      #pragma unroll
      for (int j = 0; j < 8; ++j) v[j] = (__bf16)src[i + j];
      *(bf16x8*)(dst + i) = v;
    }
  }
  // Wp0{f,b}: [2048][768]; perm row rr: u=rr>>2,g=rr&3, orig row R=g*512+u
  for (unsigned task = gtid; task < 2u * 2048 * 6; task += 65536) {
    unsigned dir = task / (2048 * 6);
    unsigned rr = (task / 6) % 2048;
    unsigned ch = task % 6;
    unsigned R = (rr & 3) * 512 + (rr >> 2);
    const float* wih = dir ? p.w_ih_0b : p.w_ih_0f;
    const float* whh = dir ? p.w_hh_0b : p.w_hh_0f;
    __bf16* dst = (dir ? p.Wp0b : p.Wp0f) + (size_t)rr * 768;
    const float* src; unsigned kd;
    if (ch < 4) { src = whh + (size_t)R * 512 + ch * 128;        kd = ch * 128; }
    else        { src = wih + (size_t)R * 256 + (ch - 4) * 128;  kd = 512 + (ch - 4) * 128; }
    for (int i = 0; i < 128; i += 8) {
      bf16x8 v;
      #pragma unroll
      for (int j = 0; j < 8; ++j) v[j] = (__bf16)src[i + j];
      *(bf16x8*)(dst + kd + i) = v;
    }
  }
  // Wp1{f,b}: [2048][1536]
  for (unsigned task = gtid; task < 2u * 2048 * 12; task += 65536) {
    unsigned dir = task / (2048 * 12);
    unsigned rr = (task / 12) % 2048;
    unsigned ch = task % 12;
    unsigned R = (rr & 3) * 512 + (rr >> 2);
    const float* wih = dir ? p.w_ih_1b : p.w_ih_1f;
    const float* whh = dir ? p.w_hh_1b : p.w_hh_1f;
    __bf16* dst = (dir ? p.Wp1b : p.Wp1f) + (size_t)rr * 1536;
    const float* src; unsigned kd;
    if (ch < 4) { src = whh + (size_t)R * 512 + ch * 128;         kd = ch * 128; }
    else        { src = wih + (size_t)R * 1024 + (ch - 4) * 128;  kd = 512 + (ch - 4) * 128; }
    for (int i = 0; i < 128; i += 8) {
      bf16x8 v;
      #pragma unroll
      for (int j = 0; j < 8; ++j) v[j] = (__bf16)src[i + j];
      *(bf16x8*)(dst + kd + i) = v;
    }
  }
  // permuted biases
  if (gtid < 4u * 2048) {
    unsigned arr = gtid >> 11, rr = gtid & 2047;
    unsigned R = (rr & 3) * 512 + (rr >> 2);
    const float* src = arr == 0 ? p.b_0f : arr == 1 ? p.b_0b : arr == 2 ? p.b_1f : p.b_1b;
    p.bp[arr * 2048 + rr] = src[R];
  }
  // h inits (bf16): y0 slab0 cols[0:512)=h0[0]; slab513 cols[512:1024)=h0[1];
  // h1buf slab2=h0[2]; h1binit=h0[3]
  if (gtid < 4u * 4096) {
    unsigned dl = gtid >> 12;
    unsigned e = (gtid & 4095) * 8;
    unsigned b = e >> 9, u = e & 511;
    const float* src = p.h0 + (size_t)dl * 64 * 512 + (size_t)b * 512 + u;
    __bf16* dst;
    if (dl == 0)      dst = p.y0 + ((size_t)0 * 64 + b) * 1024 + u;
    else if (dl == 1) dst = p.y0 + ((size_t)513 * 64 + b) * 1024 + 512 + u;
    else if (dl == 2) dst = p.h1buf + ((size_t)2 * 64 + b) * 512 + u;
    else              dst = p.h1binit + (size_t)b * 512 + u;
    bf16x8 v;
    #pragma unroll
    for (int j = 0; j < 8; ++j) v[j] = (__bf16)src[j];
    *(bf16x8*)dst = v;
  }

  phase_barrier(p.flags, wg, tid, 1u);

  // ---------------- P1: layer0 recurrence ----------------
  // group g = wg & 7 (fwd: 0..3, bwd: 4..7; bg = g & 3); ug = wg >> 3.
  // All 32 WGs of a group share wg % 8 -> one XCD under round-robin dispatch.
  {
    const int g = wg & 7;
    const bool fwd = g < 4;
    const int bg = g & 3;
    const int ug = wg >> 3;
    const int bbase = bg * 16;
    const int uglob = ug * 16 + wv * 4;  // this wave: 4 hidden units
    const int colbase = uglob * 4;       // 16 permuted gate cols
    const __bf16* Wp = fwd ? p.Wp0f : p.Wp0b;
    bf16x8 wf[24];                       // register-resident weights
    #pragma unroll
    for (int kb = 0; kb < 24; ++kb)
      wf[kb] = *(const bf16x8*)(Wp + (size_t)(colbase + colq) * 768 + kb * 32 + quad * 8);
    const float bias_col = p.bp[(fwd ? 0 : 1) * 2048 + colbase + colq];
    float c = p.c0[(size_t)(fwd ? 0 : 1) * 64 * 512 + (size_t)(bbase + bl) * 512 + uglob + ul];
    const int dcol = fwd ? 0 : 512;
    unsigned* gsl = p.flags + (size_t)(256 + g * 32) * SLOT;
    for (int s = 0; s < 512; ++s) {
      if (s > 0) group_wait(gsl, lane, (unsigned)s);
      const int t = fwd ? s : 511 - s;
      const int slabA = fwd ? t : t + 2;   // h(t-1) at slab t; h(t+1) at slab t+2
      const __bf16* aH = p.y0 + ((size_t)slabA * 64 + bbase + colq) * 1024 + dcol + quad * 8;
      const __bf16* aX = p.xT + ((size_t)t * 64 + bbase + colq) * 256 + quad * 8;
      f32x4 acc = {0.f, 0.f, 0.f, 0.f};
      #pragma unroll
      for (int kb = 0; kb < 16; ++kb)
        acc = __builtin_amdgcn_mfma_f32_16x16x32_bf16(*(const bf16x8*)(aH + kb * 32), wf[kb], acc, 0, 0, 0);
      #pragma unroll
      for (int kb = 0; kb < 8; ++kb)
        acc = __builtin_amdgcn_mfma_f32_16x16x32_bf16(*(const bf16x8*)(aX + kb * 32), wf[16 + kb], acc, 0, 0, 0);
      #pragma unroll
      for (int r = 0; r < 4; ++r) ldsw[(quad * 4 + r) * 16 + colq] = acc[r] + bias_col;
      __syncthreads();
      float gi = ldsw[bl * 16 + ul * 4 + 0];
      float gf = ldsw[bl * 16 + ul * 4 + 1];
      float gg = ldsw[bl * 16 + ul * 4 + 2];
      float go = ldsw[bl * 16 + ul * 4 + 3];
      c = sigm(gf) * c + sigm(gi) * tanhf(gg);
      float h = sigm(go) * tanhf(c);
      p.y0[((size_t)(t + 1) * 64 + bbase + bl) * 1024 + dcol + uglob + ul] = (__bf16)h;
      if (s < 511) group_post(gsl + (size_t)ug * SLOT, tid, (unsigned)(s + 1));
    }
  }
  phase_barrier(p.flags, wg, tid, 2u);

  // ---------------- P3: layer1 fwd ((wg&7)<4) | P4: layer1 bwd single step ----------------
  if ((wg & 7) < 4) {
    const int bg = wg & 7;               // 0..3
    const int ug = wg >> 3;
    const int bbase = bg * 16;
    const int uglob = ug * 16 + wv * 4;
    const int colbase = uglob * 4;
    bf16x8 wf[48];                       // [hh 16 | ih 32] frags
    #pragma unroll
    for (int kb = 0; kb < 48; ++kb)
      wf[kb] = *(const bf16x8*)(p.Wp1f + (size_t)(colbase + colq) * 1536 + kb * 32 + quad * 8);
    const float bias_col = p.bp[2 * 2048 + colbase + colq];
    float c = p.c0[(size_t)2 * 64 * 512 + (size_t)(bbase + bl) * 512 + uglob + ul];
    unsigned* gsl = p.flags + (size_t)(512 + bg * 32) * SLOT;
    for (int t = 0; t < 512; ++t) {
      if (t > 0) group_wait(gsl, lane, (unsigned)t);
      const int prev = (t == 0) ? 2 : ((t - 1) & 1);
      const int cur = t & 1;
      const __bf16* aH = p.h1buf + ((size_t)prev * 64 + bbase + colq) * 512 + quad * 8;
      const __bf16* aX = p.y0 + ((size_t)(t + 1) * 64 + bbase + colq) * 1024 + quad * 8;
      f32x4 acc = {0.f, 0.f, 0.f, 0.f};
      #pragma unroll
      for (int kb = 0; kb < 16; ++kb)
        acc = __builtin_amdgcn_mfma_f32_16x16x32_bf16(*(const bf16x8*)(aH + kb * 32), wf[kb], acc, 0, 0, 0);
      #pragma unroll
      for (int kb = 0; kb < 32; ++kb)
        acc = __builtin_amdgcn_mfma_f32_16x16x32_bf16(*(const bf16x8*)(aX + kb * 32), wf[16 + kb], acc, 0, 0, 0);
      #pragma unroll
      for (int r = 0; r < 4; ++r) ldsw[(quad * 4 + r) * 16 + colq] = acc[r] + bias_col;
      __syncthreads();
      float gi = ldsw[bl * 16 + ul * 4 + 0];
      float gf = ldsw[bl * 16 + ul * 4 + 1];
      float gg = ldsw[bl * 16 + ul * 4 + 2];
      float go = ldsw[bl * 16 + ul * 4 + 3];
      c = sigm(gf) * c + sigm(gi) * tanhf(gg);
      float h = sigm(go) * tanhf(c);
      p.h1buf[((size_t)cur * 64 + bbase + bl) * 512 + uglob + ul] = (__bf16)h;
      if (t < 511) group_post(gsl + (size_t)ug * SLOT, tid, (unsigned)(t + 1));
    }
  } else {
    const int bg = (wg & 7) - 4;
    const int ug = wg >> 3;
    const int bbase = bg * 16;
    const int uglob = ug * 16 + wv * 4;
    const int colbase = uglob * 4;
    const __bf16* aH = p.h1binit + (size_t)(bbase + colq) * 512 + quad * 8;
    const __bf16* aX = p.y0 + ((size_t)512 * 64 + bbase + colq) * 1024 + quad * 8;
    f32x4 acc = {0.f, 0.f, 0.f, 0.f};
    #pragma unroll
    for (int kb = 0; kb < 16; ++kb) {
      bf16x8 w = *(const bf16x8*)(p.Wp1b + (size_t)(colbase + colq) * 1536 + kb * 32 + quad * 8);
      acc = __builtin_amdgcn_mfma_f32_16x16x32_bf16(*(const bf16x8*)(aH + kb * 32), w, acc, 0, 0, 0);
    }
    #pragma unroll
    for (int kb = 0; kb < 32; ++kb) {
      bf16x8 w = *(const bf16x8*)(p.Wp1b + (size_t)(colbase + colq) * 1536 + (16 + kb) * 32 + quad * 8);
      acc = __builtin_amdgcn_mfma_f32_16x16x32_bf16(*(const bf16x8*)(aX + kb * 32), w, acc, 0, 0, 0);
    }
    const float bias_col = p.bp[3 * 2048 + colbase + colq];
    #pragma unroll
    for (int r = 0; r < 4; ++r) ldsw[(quad * 4 + r) * 16 + colq] = acc[r] + bias_col;
    __syncthreads();
    float gi = ldsw[bl * 16 + ul * 4 + 0];
    float gf = ldsw[bl * 16 + ul * 4 + 1];
    float gg = ldsw[bl * 16 + ul * 4 + 2];
    float go = ldsw[bl * 16 + ul * 4 + 3];
    float c = p.c0[(size_t)3 * 64 * 512 + (size_t)(bbase + bl) * 512 + uglob + ul];
    c = sigm(gf) * c + sigm(gi) * tanhf(gg);
    float h = sigm(go) * tanhf(c);
    p.h1bout[(size_t)(bbase + bl) * 512 + uglob + ul] = (__bf16)h;
  }
  phase_barrier(p.flags, wg, tid, 3u);

  // ---------------- FC: out[b][o] = fc_b[o] + last[b,:] . fc_w[o,:] ----------------
  if (wg < 8) {
    const int b = wg * 8 + (tid >> 5);
    const int o = (tid >> 2) & 7;
    const int ks = tid & 3;
    const int k0 = ks * 256;
    const __bf16* l1 = p.h1buf + ((size_t)1 * 64 + b) * 512;   // h1f(t=511), slab 511&1=1
    const __bf16* l2 = p.h1bout + (size_t)b * 512;             // h1b(t=511)
    const __bf16* hsrc = (ks < 2) ? (l1 + k0) : (l2 + k0 - 512);
    const float* w = p.fc_w + (size_t)o * 1024 + k0;
    float acc = 0.f;
    for (int k = 0; k < 256; ++k) acc += (float)hsrc[k] * w[k];
    acc += __shfl_down(acc, 2, 4);
    acc += __shfl_down(acc, 1, 4);
    if (ks == 0) p.out[b * 8 + o] = acc + p.fc_b[o];
  }
}

extern "C" void kernel_launch(void* const* d_in, const int* in_sizes, int n_in,
                              void* d_out, int out_size, void* d_ws, size_t ws_size,
                              hipStream_t stream) {
  char* ws = (char*)d_ws;
  Params p;
  p.input_seq = (const float*)d_in[0];
  p.h0 = (const float*)d_in[1];
  p.c0 = (const float*)d_in[2];
  p.w_ih_0f = (const float*)d_in[3];  p.w_hh_0f = (const float*)d_in[4];  p.b_0f = (const float*)d_in[5];
  p.w_ih_0b = (const float*)d_in[6];  p.w_hh_0b = (const float*)d_in[7];  p.b_0b = (const float*)d_in[8];
  p.w_ih_1f = (const float*)d_in[9];  p.w_hh_1f = (const float*)d_in[10]; p.b_1f = (const float*)d_in[11];
  p.w_ih_1b = (const float*)d_in[12]; p.w_hh_1b = (const float*)d_in[13]; p.b_1b = (const float*)d_in[14];
  p.fc_w = (const float*)d_in[15];    p.fc_b = (const float*)d_in[16];
  p.out = (float*)d_out;

  const size_t FLAG_BYTES = (size_t)640 * SLOT * 4;   // 81920 B
  size_t off = 0;
  p.flags  = (unsigned*)(ws + off); off += FLAG_BYTES;
  p.xT     = (__bf16*)(ws + off);   off += (size_t)512 * 64 * 256 * 2;
  p.Wp0f   = (__bf16*)(ws + off);   off += (size_t)2048 * 768 * 2;
  p.Wp0b   = (__bf16*)(ws + off);   off += (size_t)2048 * 768 * 2;
  p.Wp1f   = (__bf16*)(ws + off);   off += (size_t)2048 * 1536 * 2;
  p.Wp1b   = (__bf16*)(ws + off);   off += (size_t)2048 * 1536 * 2;
  p.y0     = (__bf16*)(ws + off);   off += (size_t)514 * 64 * 1024 * 2;
  p.h1buf  = (__bf16*)(ws + off);   off += (size_t)3 * 64 * 512 * 2;
  p.h1binit= (__bf16*)(ws + off);   off += (size_t)64 * 512 * 2;
  p.h1bout = (__bf16*)(ws + off);   off += (size_t)64 * 512 * 2;
  p.bp     = (float*)(ws + off);    off += (size_t)4 * 2048 * 4;
  (void)ws_size; (void)in_sizes; (void)n_in; (void)out_size;

  hipMemsetAsync(d_ws, 0, FLAG_BYTES, stream);   // zero flag slots each call
  lstm_kernel<<<dim3(256), dim3(256), 0, stream>>>(p);
}

// Round 4
// 15376.079 us; speedup vs baseline: 2.2740x; 1.1982x over previous
//
#include <hip/hip_runtime.h>
#include <hip/hip_bf16.h>

// Bidirectional 2-layer LSTM, persistent single-kernel implementation.
// I=256, H=512, L=2, D=2, O=8, B=64, S=512.
//
// Round 4: r3's fence-free design, rebuilt on pure HIP atomics (no asm blobs).
//  - ALL per-step h transport is relaxed agent-scope atomics (compiler emits
//    global_{load,store} ... sc1 -> IF coherence point). This is immune to
//    the harness's 0xAA workspace poison leaving stale lines in per-XCD L2
//    (r3's plain cached h reads were not).
//  - Producer: lanes 0..15 compute 4 units each (padded LDS, stride 17,
//    conflict-free), pack 4x bf16 -> one u64 atomic store.
//  - Producer->flag order: s_waitcnt vmcnt(0) (sc1 stores complete at IF),
//    then relaxed flag store. Consumer: parallel poll of 128 wave-flags,
//    then sc1 fragment loads (data-dependent, IF is the coherence point).
//  - Heavy fences (wbl2/inv) only at the 3 phase barriers; x/weight loads
//    are plain cached (protected by phase-barrier acquire-inv).

typedef __attribute__((ext_vector_type(8))) __bf16 bf16x8;
typedef __attribute__((ext_vector_type(4))) float f32x4;

struct Params {
  const float *input_seq, *h0, *c0;
  const float *w_ih_0f, *w_hh_0f, *b_0f;
  const float *w_ih_0b, *w_hh_0b, *b_0b;
  const float *w_ih_1f, *w_hh_1f, *b_1f;
  const float *w_ih_1b, *w_hh_1b, *b_1b;
  const float *fc_w, *fc_b;
  float* out;
  unsigned* flags;        // dense u32: [0,256) phase; [256,1280) L0 8 grp x 128 waves; [1280,1792) L1 4 grp x 128
  __bf16* xT;             // [512][64][256]  time-major bf16 input
  __bf16* Wp0f; __bf16* Wp0b;   // [2048 perm rows][768 = 512 hh | 256 ih]
  __bf16* Wp1f; __bf16* Wp1b;   // [2048 perm rows][1536 = 512 hh | 1024 ih]
  __bf16* y0;             // [514][64][1024]; slab s = t+1; slab0/513 = inits
  __bf16* h1buf;          // [3][64][512]; slabs 0/1 ping-pong, 2 = init
  __bf16* h1binit;        // [64][512]
  __bf16* h1bout;         // [64][512]
  float* bp;              // [4][2048] permuted biases (0f,0b,1f,1b)
};

__device__ __forceinline__ float sigm(float x) { return 1.f / (1.f + __expf(-x)); }

// Phase barrier (3 uses): publishes plain cached writes across XCDs
// (release fence -> s_waitcnt + buffer_wbl2; acquire fence -> buffer_inv).
__device__ __forceinline__ void phase_barrier(unsigned* pf, int wg, int tid, unsigned phase) {
  __syncthreads();
  if (tid == 0) {
    __builtin_amdgcn_fence(__ATOMIC_RELEASE, "agent");
    __hip_atomic_store(pf + wg, phase, __ATOMIC_RELAXED, __HIP_MEMORY_SCOPE_AGENT);
  }
  bool ok;
  do {
    unsigned v = __hip_atomic_load(pf + tid, __ATOMIC_RELAXED, __HIP_MEMORY_SCOPE_AGENT);
    ok = v >= phase;
    if (!ok) __builtin_amdgcn_s_sleep(8);
  } while (!__syncthreads_and(ok));
  __builtin_amdgcn_fence(__ATOMIC_ACQUIRE, "agent");
}

// Consumer: wait until all 128 wave-flags of the group >= need (64 lanes poll
// 2 flags each -> one IF round trip per iteration). sc1 atomic loads.
__device__ __forceinline__ void group_wait128(const unsigned* base, int lane, unsigned need) {
  for (;;) {
    unsigned v0 = __hip_atomic_load(base + lane,      __ATOMIC_RELAXED, __HIP_MEMORY_SCOPE_AGENT);
    unsigned v1 = __hip_atomic_load(base + 64 + lane, __ATOMIC_RELAXED, __HIP_MEMORY_SCOPE_AGENT);
    bool ok = (v0 >= need) && (v1 >= need);
    if (__ballot(ok) == ~0ull) break;
    __builtin_amdgcn_s_sleep(1);
  }
  asm volatile("" ::: "memory");   // no hoisting of h loads above the poll
}

// Producer (per wave): drain own vmem (sc1 h stores completed at IF), post flag.
__device__ __forceinline__ void wave_post(unsigned* slot, int lane, unsigned val) {
  asm volatile("s_waitcnt vmcnt(0)" ::: "memory");
  if (lane == 0)
    __hip_atomic_store(slot, val, __ATOMIC_RELAXED, __HIP_MEMORY_SCOPE_AGENT);
}

// Device-coherent 16-B fragment load as 2x u64 relaxed agent atomics (sc1).
__device__ __forceinline__ bf16x8 load_h8_coh(const __bf16* ptr) {
  const unsigned long long* q = (const unsigned long long*)ptr;
  unsigned long long lo = __hip_atomic_load(q,     __ATOMIC_RELAXED, __HIP_MEMORY_SCOPE_AGENT);
  unsigned long long hi = __hip_atomic_load(q + 1, __ATOMIC_RELAXED, __HIP_MEMORY_SCOPE_AGENT);
  union { unsigned long long w[2]; bf16x8 v; } u;
  u.w[0] = lo; u.w[1] = hi;
  return u.v;
}

__global__ __launch_bounds__(256, 2) void lstm_kernel(Params p) {
  const int tid  = threadIdx.x;
  const int wg   = blockIdx.x;
  const unsigned gtid = wg * 256 + tid;
  const int lane = tid & 63;
  const int wv   = tid >> 6;          // wave 0..3
  const int colq = lane & 15;         // A-operand batch row m / B-operand gate col n
  const int quad = lane >> 4;         // k-subblock selector

  __shared__ float lds[4][272];       // padded stride 17: conflict-free reads
  float* ldsw = lds[wv];              // wave-private slab

  // ---------------- prologue: pack/permute/convert ----------------
  { // xT[t][b][:] = bf16(input_seq[b][t][:])
    int row = gtid >> 1, half = gtid & 1;
    int t = row >> 6, b = row & 63;
    const float* src = p.input_seq + ((size_t)b * 512 + t) * 256 + half * 128;
    __bf16* dst = p.xT + (size_t)row * 256 + half * 128;
    for (int i = 0; i < 128; i += 8) {
      bf16x8 v;
      #pragma unroll
      for (int j = 0; j < 8; ++j) v[j] = (__bf16)src[i + j];
      *(bf16x8*)(dst + i) = v;
    }
  }
  // Wp0{f,b}: [2048][768]; perm row rr: u=rr>>2,g=rr&3, orig row R=g*512+u
  for (unsigned task = gtid; task < 2u * 2048 * 6; task += 65536) {
    unsigned dir = task / (2048 * 6);
    unsigned rr = (task / 6) % 2048;
    unsigned ch = task % 6;
    unsigned R = (rr & 3) * 512 + (rr >> 2);
    const float* wih = dir ? p.w_ih_0b : p.w_ih_0f;
    const float* whh = dir ? p.w_hh_0b : p.w_hh_0f;
    __bf16* dst = (dir ? p.Wp0b : p.Wp0f) + (size_t)rr * 768;
    const float* src; unsigned kd;
    if (ch < 4) { src = whh + (size_t)R * 512 + ch * 128;        kd = ch * 128; }
    else        { src = wih + (size_t)R * 256 + (ch - 4) * 128;  kd = 512 + (ch - 4) * 128; }
    for (int i = 0; i < 128; i += 8) {
      bf16x8 v;
      #pragma unroll
      for (int j = 0; j < 8; ++j) v[j] = (__bf16)src[i + j];
      *(bf16x8*)(dst + kd + i) = v;
    }
  }
  // Wp1{f,b}: [2048][1536]
  for (unsigned task = gtid; task < 2u * 2048 * 12; task += 65536) {
    unsigned dir = task / (2048 * 12);
    unsigned rr = (task / 12) % 2048;
    unsigned ch = task % 12;
    unsigned R = (rr & 3) * 512 + (rr >> 2);
    const float* wih = dir ? p.w_ih_1b : p.w_ih_1f;
    const float* whh = dir ? p.w_hh_1b : p.w_hh_1f;
    __bf16* dst = (dir ? p.Wp1b : p.Wp1f) + (size_t)rr * 1536;
    const float* src; unsigned kd;
    if (ch < 4) { src = whh + (size_t)R * 512 + ch * 128;         kd = ch * 128; }
    else        { src = wih + (size_t)R * 1024 + (ch - 4) * 128;  kd = 512 + (ch - 4) * 128; }
    for (int i = 0; i < 128; i += 8) {
      bf16x8 v;
      #pragma unroll
      for (int j = 0; j < 8; ++j) v[j] = (__bf16)src[i + j];
      *(bf16x8*)(dst + kd + i) = v;
    }
  }
  // permuted biases
  if (gtid < 4u * 2048) {
    unsigned arr = gtid >> 11, rr = gtid & 2047;
    unsigned R = (rr & 3) * 512 + (rr >> 2);
    const float* src = arr == 0 ? p.b_0f : arr == 1 ? p.b_0b : arr == 2 ? p.b_1f : p.b_1b;
    p.bp[arr * 2048 + rr] = src[R];
  }
  // h inits (bf16)
  if (gtid < 4u * 4096) {
    unsigned dl = gtid >> 12;
    unsigned e = (gtid & 4095) * 8;
    unsigned b = e >> 9, u = e & 511;
    const float* src = p.h0 + (size_t)dl * 64 * 512 + (size_t)b * 512 + u;
    __bf16* dst;
    if (dl == 0)      dst = p.y0 + ((size_t)0 * 64 + b) * 1024 + u;
    else if (dl == 1) dst = p.y0 + ((size_t)513 * 64 + b) * 1024 + 512 + u;
    else if (dl == 2) dst = p.h1buf + ((size_t)2 * 64 + b) * 512 + u;
    else              dst = p.h1binit + (size_t)b * 512 + u;
    bf16x8 v;
    #pragma unroll
    for (int j = 0; j < 8; ++j) v[j] = (__bf16)src[j];
    *(bf16x8*)dst = v;
  }

  phase_barrier(p.flags, wg, tid, 1u);

  // ---------------- P1: layer0 recurrence ----------------
  // group g = wg & 7 (fwd: 0..3, bwd: 4..7; bg = g & 3); ug = wg >> 3.
  {
    const int g = wg & 7;
    const bool fwd = g < 4;
    const int bg = g & 3;
    const int ug = wg >> 3;
    const int bbase = bg * 16;
    const int uglob = ug * 16 + wv * 4;  // this wave: 4 hidden units
    const int colbase = uglob * 4;       // 16 permuted gate cols
    const __bf16* Wp = fwd ? p.Wp0f : p.Wp0b;
    bf16x8 wf[24];
    #pragma unroll
    for (int kb = 0; kb < 24; ++kb)
      wf[kb] = *(const bf16x8*)(Wp + (size_t)(colbase + colq) * 768 + kb * 32 + quad * 8);
    const float bias_col = p.bp[(fwd ? 0 : 1) * 2048 + colbase + colq];
    f32x4 cc = {0.f, 0.f, 0.f, 0.f};     // lanes<16: c for 4 units of batch row (bbase+lane)
    if (lane < 16)
      cc = *(const f32x4*)(p.c0 + (size_t)(fwd ? 0 : 1) * 64 * 512 + (size_t)(bbase + lane) * 512 + uglob);
    const int dcol = fwd ? 0 : 512;
    unsigned* gfl = p.flags + 256 + g * 128;
    const int myslot = ug * 4 + wv;
    for (int s = 0; s < 512; ++s) {
      const int t = fwd ? s : 511 - s;
      const int slabA = fwd ? t : t + 2;   // h(t-1) at slab t; h(t+1) at slab t+2
      // prefetch x fragments (plain cached, prologue data) under the wait
      const __bf16* aX = p.xT + ((size_t)t * 64 + bbase + colq) * 256 + quad * 8;
      bf16x8 xf[8];
      #pragma unroll
      for (int kb = 0; kb < 8; ++kb) xf[kb] = *(const bf16x8*)(aX + kb * 32);
      if (s > 0) group_wait128(gfl, lane, (unsigned)s);
      // h fragments: device-coherent sc1 loads from IF
      const __bf16* aH = p.y0 + ((size_t)slabA * 64 + bbase + colq) * 1024 + dcol + quad * 8;
      bf16x8 hf[16];
      #pragma unroll
      for (int kb = 0; kb < 16; ++kb) hf[kb] = load_h8_coh(aH + kb * 32);
      f32x4 acc = {0.f, 0.f, 0.f, 0.f};
      #pragma unroll
      for (int kb = 0; kb < 8; ++kb)
        acc = __builtin_amdgcn_mfma_f32_16x16x32_bf16(xf[kb], wf[16 + kb], acc, 0, 0, 0);
      #pragma unroll
      for (int kb = 0; kb < 16; ++kb)
        acc = __builtin_amdgcn_mfma_f32_16x16x32_bf16(hf[kb], wf[kb], acc, 0, 0, 0);
      #pragma unroll
      for (int r = 0; r < 4; ++r) ldsw[(quad * 4 + r) * 17 + colq] = acc[r] + bias_col;
      if (lane < 16) {                   // batch row bbase+lane, 4 units
        unsigned long long pack = 0;
        #pragma unroll
        for (int j = 0; j < 4; ++j) {
          float gi = ldsw[lane * 17 + j * 4 + 0];
          float gf = ldsw[lane * 17 + j * 4 + 1];
          float gg = ldsw[lane * 17 + j * 4 + 2];
          float go = ldsw[lane * 17 + j * 4 + 3];
          float cj = sigm(gf) * cc[j] + sigm(gi) * tanhf(gg);
          cc[j] = cj;
          float h = sigm(go) * tanhf(cj);
          __bf16 hb = (__bf16)h;
          unsigned short hu; __builtin_memcpy(&hu, &hb, 2);
          pack |= (unsigned long long)hu << (16 * j);
        }
        unsigned long long* hdst = (unsigned long long*)
          (p.y0 + ((size_t)(t + 1) * 64 + bbase + lane) * 1024 + dcol + uglob);
        __hip_atomic_store(hdst, pack, __ATOMIC_RELAXED, __HIP_MEMORY_SCOPE_AGENT);
      }
      if (s < 511) wave_post(gfl + myslot, lane, (unsigned)(s + 1));
    }
  }
  phase_barrier(p.flags, wg, tid, 2u);

  // ---------------- P3: layer1 fwd ((wg&7)<4) | P4: layer1 bwd single step ----------------
  if ((wg & 7) < 4) {
    const int bg = wg & 7;
    const int ug = wg >> 3;
    const int bbase = bg * 16;
    const int uglob = ug * 16 + wv * 4;
    const int colbase = uglob * 4;
    const float bias_col = p.bp[2 * 2048 + colbase + colq];
    f32x4 cc = {0.f, 0.f, 0.f, 0.f};
    if (lane < 16)
      cc = *(const f32x4*)(p.c0 + (size_t)2 * 64 * 512 + (size_t)(bbase + lane) * 512 + uglob);
    unsigned* gfl = p.flags + 1280 + bg * 128;
    const int myslot = ug * 4 + wv;
    const __bf16* wrow = p.Wp1f + (size_t)(colbase + colq) * 1536;
    for (int t = 0; t < 512; ++t) {
      // prefetch x = y0 slab t+1 (P1 output, plain cached: caches were
      // invalidated at phase_barrier 2, so misses fetch fresh from IF)
      const __bf16* aX = p.y0 + ((size_t)(t + 1) * 64 + bbase + colq) * 1024 + quad * 8;
      bf16x8 xf[32];
      #pragma unroll
      for (int kb = 0; kb < 32; ++kb) xf[kb] = *(const bf16x8*)(aX + kb * 32);
      if (t > 0) group_wait128(gfl, lane, (unsigned)t);
      const int prev = (t == 0) ? 2 : ((t - 1) & 1);
      const int cur = t & 1;
      // h ping-pong addresses are reused -> sc1 loads mandatory
      const __bf16* aH = p.h1buf + ((size_t)prev * 64 + bbase + colq) * 512 + quad * 8;
      bf16x8 hf[16];
      #pragma unroll
      for (int kb = 0; kb < 16; ++kb) hf[kb] = load_h8_coh(aH + kb * 32);
      f32x4 acc = {0.f, 0.f, 0.f, 0.f};
      #pragma unroll
      for (int kb = 0; kb < 32; ++kb)
        acc = __builtin_amdgcn_mfma_f32_16x16x32_bf16(xf[kb], *(const bf16x8*)(wrow + (16 + kb) * 32 + quad * 8), acc, 0, 0, 0);
      #pragma unroll
      for (int kb = 0; kb < 16; ++kb)
        acc = __builtin_amdgcn_mfma_f32_16x16x32_bf16(hf[kb], *(const bf16x8*)(wrow + kb * 32 + quad * 8), acc, 0, 0, 0);
      #pragma unroll
      for (int r = 0; r < 4; ++r) ldsw[(quad * 4 + r) * 17 + colq] = acc[r] + bias_col;
      if (lane < 16) {
        unsigned long long pack = 0;
        #pragma unroll
        for (int j = 0; j < 4; ++j) {
          float gi = ldsw[lane * 17 + j * 4 + 0];
          float gf = ldsw[lane * 17 + j * 4 + 1];
          float gg = ldsw[lane * 17 + j * 4 + 2];
          float go = ldsw[lane * 17 + j * 4 + 3];
          float cj = sigm(gf) * cc[j] + sigm(gi) * tanhf(gg);
          cc[j] = cj;
          float h = sigm(go) * tanhf(cj);
          __bf16 hb = (__bf16)h;
          unsigned short hu; __builtin_memcpy(&hu, &hb, 2);
          pack |= (unsigned long long)hu << (16 * j);
        }
        unsigned long long* hdst = (unsigned long long*)
          (p.h1buf + ((size_t)cur * 64 + bbase + lane) * 512 + uglob);
        __hip_atomic_store(hdst, pack, __ATOMIC_RELAXED, __HIP_MEMORY_SCOPE_AGENT);
      }
      if (t < 511) wave_post(gfl + myslot, lane, (unsigned)(t + 1));
    }
  } else {
    const int bg = (wg & 7) - 4;
    const int ug = wg >> 3;
    const int bbase = bg * 16;
    const int uglob = ug * 16 + wv * 4;
    const int colbase = uglob * 4;
    // P1 outputs + prologue data, plain cached (post-barrier2, caches clean)
    const __bf16* aH = p.h1binit + (size_t)(bbase + colq) * 512 + quad * 8;
    const __bf16* aX = p.y0 + ((size_t)512 * 64 + bbase + colq) * 1024 + quad * 8;
    const __bf16* wrow = p.Wp1b + (size_t)(colbase + colq) * 1536;
    f32x4 acc = {0.f, 0.f, 0.f, 0.f};
    #pragma unroll
    for (int kb = 0; kb < 16; ++kb)
      acc = __builtin_amdgcn_mfma_f32_16x16x32_bf16(*(const bf16x8*)(aH + kb * 32), *(const bf16x8*)(wrow + kb * 32 + quad * 8), acc, 0, 0, 0);
    #pragma unroll
    for (int kb = 0; kb < 32; ++kb)
      acc = __builtin_amdgcn_mfma_f32_16x16x32_bf16(*(const bf16x8*)(aX + kb * 32), *(const bf16x8*)(wrow + (16 + kb) * 32 + quad * 8), acc, 0, 0, 0);
    const float bias_col = p.bp[3 * 2048 + colbase + colq];
    #pragma unroll
    for (int r = 0; r < 4; ++r) ldsw[(quad * 4 + r) * 17 + colq] = acc[r] + bias_col;
    if (lane < 16) {
      f32x4 cc = *(const f32x4*)(p.c0 + (size_t)3 * 64 * 512 + (size_t)(bbase + lane) * 512 + uglob);
      unsigned long long pack = 0;
      #pragma unroll
      for (int j = 0; j < 4; ++j) {
        float gi = ldsw[lane * 17 + j * 4 + 0];
        float gf = ldsw[lane * 17 + j * 4 + 1];
        float gg = ldsw[lane * 17 + j * 4 + 2];
        float go = ldsw[lane * 17 + j * 4 + 3];
        float cj = sigm(gf) * cc[j] + sigm(gi) * tanhf(gg);
        float h = sigm(go) * tanhf(cj);
        __bf16 hb = (__bf16)h;
        unsigned short hu; __builtin_memcpy(&hu, &hb, 2);
        pack |= (unsigned long long)hu << (16 * j);
      }
      unsigned long long* hdst = (unsigned long long*)
        (p.h1bout + (size_t)(bbase + lane) * 512 + uglob);
      __hip_atomic_store(hdst, pack, __ATOMIC_RELAXED, __HIP_MEMORY_SCOPE_AGENT);
    }
  }
  phase_barrier(p.flags, wg, tid, 3u);

  // ---------------- FC: out[b][o] = fc_b[o] + last[b,:] . fc_w[o,:] ----------------
  if (wg < 8) {
    const int b = wg * 8 + (tid >> 5);
    const int o = (tid >> 2) & 7;
    const int ks = tid & 3;
    const int k0 = ks * 256;
    const __bf16* l1 = p.h1buf + ((size_t)1 * 64 + b) * 512;   // h1f(t=511), slab 511&1=1
    const __bf16* l2 = p.h1bout + (size_t)b * 512;             // h1b(t=511)
    const __bf16* hsrc = (ks < 2) ? (l1 + k0) : (l2 + k0 - 512);
    const float* w = p.fc_w + (size_t)o * 1024 + k0;
    float acc = 0.f;
    for (int k = 0; k < 256; ++k) acc += (float)hsrc[k] * w[k];
    acc += __shfl_down(acc, 2, 4);
    acc += __shfl_down(acc, 1, 4);
    if (ks == 0) p.out[b * 8 + o] = acc + p.fc_b[o];
  }
}

extern "C" void kernel_launch(void* const* d_in, const int* in_sizes, int n_in,
                              void* d_out, int out_size, void* d_ws, size_t ws_size,
                              hipStream_t stream) {
  char* ws = (char*)d_ws;
  Params p;
  p.input_seq = (const float*)d_in[0];
  p.h0 = (const float*)d_in[1];
  p.c0 = (const float*)d_in[2];
  p.w_ih_0f = (const float*)d_in[3];  p.w_hh_0f = (const float*)d_in[4];  p.b_0f = (const float*)d_in[5];
  p.w_ih_0b = (const float*)d_in[6];  p.w_hh_0b = (const float*)d_in[7];  p.b_0b = (const float*)d_in[8];
  p.w_ih_1f = (const float*)d_in[9];  p.w_hh_1f = (const float*)d_in[10]; p.b_1f = (const float*)d_in[11];
  p.w_ih_1b = (const float*)d_in[12]; p.w_hh_1b = (const float*)d_in[13]; p.b_1b = (const float*)d_in[14];
  p.fc_w = (const float*)d_in[15];    p.fc_b = (const float*)d_in[16];
  p.out = (float*)d_out;

  const size_t FLAG_BYTES = 8192;      // 1792 dense u32 flags (rounded up)
  size_t off = 0;
  p.flags  = (unsigned*)(ws + off); off += FLAG_BYTES;
  p.xT     = (__bf16*)(ws + off);   off += (size_t)512 * 64 * 256 * 2;
  p.Wp0f   = (__bf16*)(ws + off);   off += (size_t)2048 * 768 * 2;
  p.Wp0b   = (__bf16*)(ws + off);   off += (size_t)2048 * 768 * 2;
  p.Wp1f   = (__bf16*)(ws + off);   off += (size_t)2048 * 1536 * 2;
  p.Wp1b   = (__bf16*)(ws + off);   off += (size_t)2048 * 1536 * 2;
  p.y0     = (__bf16*)(ws + off);   off += (size_t)514 * 64 * 1024 * 2;
  p.h1buf  = (__bf16*)(ws + off);   off += (size_t)3 * 64 * 512 * 2;
  p.h1binit= (__bf16*)(ws + off);   off += (size_t)64 * 512 * 2;
  p.h1bout = (__bf16*)(ws + off);   off += (size_t)64 * 512 * 2;
  p.bp     = (float*)(ws + off);    off += (size_t)4 * 2048 * 4;
  (void)ws_size; (void)in_sizes; (void)n_in; (void)out_size;

  hipMemsetAsync(d_ws, 0, FLAG_BYTES, stream);   // zero flag slots each call
  lstm_kernel<<<dim3(256), dim3(256), 0, stream>>>(p);
}

// Round 5
// 12972.916 us; speedup vs baseline: 2.6952x; 1.1852x over previous
//
#include <hip/hip_runtime.h>
#include <hip/hip_bf16.h>

// Bidirectional 2-layer LSTM, persistent single-kernel implementation.
// I=256, H=512, L=2, D=2, O=8, B=64, S=512.
//
// Round 5: L2-multicast h broadcast.
//  - Producer h stores: relaxed agent-scope u64 atomics (sc1 -> IF coherence
//    point), ordered before the per-wave flag by s_waitcnt vmcnt(0).
//  - Consumer h loads: PLAIN CACHED dwordx4. Safe because every h address is
//    write-once within the dispatch (y0 slabs; NEW y1f slab buffer replaces
//    the r4 ping-pong) and kernel-launch acquire invalidates L1/L2, so the
//    first touch must miss to IF (fresh), then L2 multicasts to the other
//    31 WGs of the group. r4's sc1 consumer loads bypassed L2 -> 6.5 GB
//    fabric traffic (512x redundancy); this cuts it to ~unique+multicast.
//  - P3 weights back to register-resident wf[48] (r4 streamed them from L2
//    every MFMA).
//  - Heavy fences (wbl2/inv) only at the 3 phase barriers.

typedef __attribute__((ext_vector_type(8))) __bf16 bf16x8;
typedef __attribute__((ext_vector_type(4))) float f32x4;

struct Params {
  const float *input_seq, *h0, *c0;
  const float *w_ih_0f, *w_hh_0f, *b_0f;
  const float *w_ih_0b, *w_hh_0b, *b_0b;
  const float *w_ih_1f, *w_hh_1f, *b_1f;
  const float *w_ih_1b, *w_hh_1b, *b_1b;
  const float *fc_w, *fc_b;
  float* out;
  unsigned* flags;        // dense u32: [0,256) phase; [256,1280) L0 8 grp x 128 waves; [1280,1792) L1 4 grp x 128
  __bf16* xT;             // [512][64][256]  time-major bf16 input
  __bf16* Wp0f; __bf16* Wp0b;   // [2048 perm rows][768 = 512 hh | 256 ih]
  __bf16* Wp1f; __bf16* Wp1b;   // [2048 perm rows][1536 = 512 hh | 1024 ih]
  __bf16* y0;             // [514][64][1024]; slab s = t+1; slab0/513 = inits (write-once)
  __bf16* y1f;            // [513][64][512]; slab t+1 = h1f(t); slab0 = h0[2] init (write-once)
  __bf16* h1binit;        // [64][512]
  __bf16* h1bout;         // [64][512]
  float* bp;              // [4][2048] permuted biases (0f,0b,1f,1b)
};

__device__ __forceinline__ float sigm(float x) { return 1.f / (1.f + __expf(-x)); }

// Phase barrier (3 uses): publishes plain cached writes across XCDs
// (release fence -> wbl2; acquire fence -> inv).
__device__ __forceinline__ void phase_barrier(unsigned* pf, int wg, int tid, unsigned phase) {
  __syncthreads();
  if (tid == 0) {
    __builtin_amdgcn_fence(__ATOMIC_RELEASE, "agent");
    __hip_atomic_store(pf + wg, phase, __ATOMIC_RELAXED, __HIP_MEMORY_SCOPE_AGENT);
  }
  bool ok;
  do {
    unsigned v = __hip_atomic_load(pf + tid, __ATOMIC_RELAXED, __HIP_MEMORY_SCOPE_AGENT);
    ok = v >= phase;
    if (!ok) __builtin_amdgcn_s_sleep(8);
  } while (!__syncthreads_and(ok));
  __builtin_amdgcn_fence(__ATOMIC_ACQUIRE, "agent");
}

// Consumer: wait until all 128 wave-flags of the group >= need (64 lanes poll
// 2 flags each -> one IF round trip per iteration). sc1 atomic loads.
__device__ __forceinline__ void group_wait128(const unsigned* base, int lane, unsigned need) {
  for (;;) {
    unsigned v0 = __hip_atomic_load(base + lane,      __ATOMIC_RELAXED, __HIP_MEMORY_SCOPE_AGENT);
    unsigned v1 = __hip_atomic_load(base + 64 + lane, __ATOMIC_RELAXED, __HIP_MEMORY_SCOPE_AGENT);
    bool ok = (v0 >= need) && (v1 >= need);
    if (__ballot(ok) == ~0ull) break;
    __builtin_amdgcn_s_sleep(1);
  }
  asm volatile("" ::: "memory");   // no hoisting of h loads above the poll
}

// Producer (per wave): drain own vmem (sc1 h stores completed at IF), post flag.
__device__ __forceinline__ void wave_post(unsigned* slot, int lane, unsigned val) {
  asm volatile("s_waitcnt vmcnt(0)" ::: "memory");
  if (lane == 0)
    __hip_atomic_store(slot, val, __ATOMIC_RELAXED, __HIP_MEMORY_SCOPE_AGENT);
}

__global__ __launch_bounds__(256, 2) void lstm_kernel(Params p) {
  const int tid  = threadIdx.x;
  const int wg   = blockIdx.x;
  const unsigned gtid = wg * 256 + tid;
  const int lane = tid & 63;
  const int wv   = tid >> 6;          // wave 0..3
  const int colq = lane & 15;         // A-operand batch row m / B-operand gate col n
  const int quad = lane >> 4;         // k-subblock selector

  __shared__ float lds[4][272];       // stride 17: conflict-light
  float* ldsw = lds[wv];              // wave-private slab

  // ---------------- prologue: pack/permute/convert ----------------
  { // xT[t][b][:] = bf16(input_seq[b][t][:])
    int row = gtid >> 1, half = gtid & 1;
    int t = row >> 6, b = row & 63;
    const float* src = p.input_seq + ((size_t)b * 512 + t) * 256 + half * 128;
    __bf16* dst = p.xT + (size_t)row * 256 + half * 128;
    for (int i = 0; i < 128; i += 8) {
      bf16x8 v;
      #pragma unroll
      for (int j = 0; j < 8; ++j) v[j] = (__bf16)src[i + j];
      *(bf16x8*)(dst + i) = v;
    }
  }
  // Wp0{f,b}: [2048][768]; perm row rr: u=rr>>2,g=rr&3, orig row R=g*512+u
  for (unsigned task = gtid; task < 2u * 2048 * 6; task += 65536) {
    unsigned dir = task / (2048 * 6);
    unsigned rr = (task / 6) % 2048;
    unsigned ch = task % 6;
    unsigned R = (rr & 3) * 512 + (rr >> 2);
    const float* wih = dir ? p.w_ih_0b : p.w_ih_0f;
    const float* whh = dir ? p.w_hh_0b : p.w_hh_0f;
    __bf16* dst = (dir ? p.Wp0b : p.Wp0f) + (size_t)rr * 768;
    const float* src; unsigned kd;
    if (ch < 4) { src = whh + (size_t)R * 512 + ch * 128;        kd = ch * 128; }
    else        { src = wih + (size_t)R * 256 + (ch - 4) * 128;  kd = 512 + (ch - 4) * 128; }
    for (int i = 0; i < 128; i += 8) {
      bf16x8 v;
      #pragma unroll
      for (int j = 0; j < 8; ++j) v[j] = (__bf16)src[i + j];
      *(bf16x8*)(dst + kd + i) = v;
    }
  }
  // Wp1{f,b}: [2048][1536]
  for (unsigned task = gtid; task < 2u * 2048 * 12; task += 65536) {
    unsigned dir = task / (2048 * 12);
    unsigned rr = (task / 12) % 2048;
    unsigned ch = task % 12;
    unsigned R = (rr & 3) * 512 + (rr >> 2);
    const float* wih = dir ? p.w_ih_1b : p.w_ih_1f;
    const float* whh = dir ? p.w_hh_1b : p.w_hh_1f;
    __bf16* dst = (dir ? p.Wp1b : p.Wp1f) + (size_t)rr * 1536;
    const float* src; unsigned kd;
    if (ch < 4) { src = whh + (size_t)R * 512 + ch * 128;         kd = ch * 128; }
    else        { src = wih + (size_t)R * 1024 + (ch - 4) * 128;  kd = 512 + (ch - 4) * 128; }
    for (int i = 0; i < 128; i += 8) {
      bf16x8 v;
      #pragma unroll
      for (int j = 0; j < 8; ++j) v[j] = (__bf16)src[i + j];
      *(bf16x8*)(dst + kd + i) = v;
    }
  }
  // permuted biases
  if (gtid < 4u * 2048) {
    unsigned arr = gtid >> 11, rr = gtid & 2047;
    unsigned R = (rr & 3) * 512 + (rr >> 2);
    const float* src = arr == 0 ? p.b_0f : arr == 1 ? p.b_0b : arr == 2 ? p.b_1f : p.b_1b;
    p.bp[arr * 2048 + rr] = src[R];
  }
  // h inits (bf16): y0 slab0 lo=h0[0]; y0 slab513 hi=h0[1]; y1f slab0=h0[2]; h1binit=h0[3]
  if (gtid < 4u * 4096) {
    unsigned dl = gtid >> 12;
    unsigned e = (gtid & 4095) * 8;
    unsigned b = e >> 9, u = e & 511;
    const float* src = p.h0 + (size_t)dl * 64 * 512 + (size_t)b * 512 + u;
    __bf16* dst;
    if (dl == 0)      dst = p.y0 + ((size_t)0 * 64 + b) * 1024 + u;
    else if (dl == 1) dst = p.y0 + ((size_t)513 * 64 + b) * 1024 + 512 + u;
    else if (dl == 2) dst = p.y1f + ((size_t)0 * 64 + b) * 512 + u;
    else              dst = p.h1binit + (size_t)b * 512 + u;
    bf16x8 v;
    #pragma unroll
    for (int j = 0; j < 8; ++j) v[j] = (__bf16)src[j];
    *(bf16x8*)dst = v;
  }

  phase_barrier(p.flags, wg, tid, 1u);

  // ---------------- P1: layer0 recurrence ----------------
  // group g = wg & 7 (fwd: 0..3, bwd: 4..7; bg = g & 3); ug = wg >> 3.
  {
    const int g = wg & 7;
    const bool fwd = g < 4;
    const int bg = g & 3;
    const int ug = wg >> 3;
    const int bbase = bg * 16;
    const int uglob = ug * 16 + wv * 4;  // this wave: 4 hidden units
    const int colbase = uglob * 4;       // 16 permuted gate cols
    const __bf16* Wp = fwd ? p.Wp0f : p.Wp0b;
    bf16x8 wf[24];
    #pragma unroll
    for (int kb = 0; kb < 24; ++kb)
      wf[kb] = *(const bf16x8*)(Wp + (size_t)(colbase + colq) * 768 + kb * 32 + quad * 8);
    const float bias_col = p.bp[(fwd ? 0 : 1) * 2048 + colbase + colq];
    f32x4 cc = {0.f, 0.f, 0.f, 0.f};     // lanes<16: c for 4 units of batch row (bbase+lane)
    if (lane < 16)
      cc = *(const f32x4*)(p.c0 + (size_t)(fwd ? 0 : 1) * 64 * 512 + (size_t)(bbase + lane) * 512 + uglob);
    const int dcol = fwd ? 0 : 512;
    unsigned* gfl = p.flags + 256 + g * 128;
    const int myslot = ug * 4 + wv;
    for (int s = 0; s < 512; ++s) {
      const int t = fwd ? s : 511 - s;
      const int slabA = fwd ? t : t + 2;   // h(t-1) at slab t; h(t+1) at slab t+2
      // prefetch x fragments (plain cached) under the wait
      const __bf16* aX = p.xT + ((size_t)t * 64 + bbase + colq) * 256 + quad * 8;
      bf16x8 xf[8];
      #pragma unroll
      for (int kb = 0; kb < 8; ++kb) xf[kb] = *(const bf16x8*)(aX + kb * 32);
      if (s > 0) group_wait128(gfl, lane, (unsigned)s);
      // h fragments: PLAIN cached loads (write-once slab; first touch misses
      // to IF which holds the producer's sc1 data; L2 multicasts to the group)
      const __bf16* aH = p.y0 + ((size_t)slabA * 64 + bbase + colq) * 1024 + dcol + quad * 8;
      f32x4 acc = {0.f, 0.f, 0.f, 0.f};
      #pragma unroll
      for (int kb = 0; kb < 8; ++kb)
        acc = __builtin_amdgcn_mfma_f32_16x16x32_bf16(xf[kb], wf[16 + kb], acc, 0, 0, 0);
      #pragma unroll
      for (int kb = 0; kb < 16; ++kb)
        acc = __builtin_amdgcn_mfma_f32_16x16x32_bf16(*(const bf16x8*)(aH + kb * 32), wf[kb], acc, 0, 0, 0);
      #pragma unroll
      for (int r = 0; r < 4; ++r) ldsw[(quad * 4 + r) * 17 + colq] = acc[r] + bias_col;
      if (lane < 16) {                   // batch row bbase+lane, 4 units
        unsigned long long pack = 0;
        #pragma unroll
        for (int j = 0; j < 4; ++j) {
          float gi = ldsw[lane * 17 + j * 4 + 0];
          float gf = ldsw[lane * 17 + j * 4 + 1];
          float gg = ldsw[lane * 17 + j * 4 + 2];
          float go = ldsw[lane * 17 + j * 4 + 3];
          float cj = sigm(gf) * cc[j] + sigm(gi) * tanhf(gg);
          cc[j] = cj;
          float h = sigm(go) * tanhf(cj);
          __bf16 hb = (__bf16)h;
          unsigned short hu; __builtin_memcpy(&hu, &hb, 2);
          pack |= (unsigned long long)hu << (16 * j);
        }
        unsigned long long* hdst = (unsigned long long*)
          (p.y0 + ((size_t)(t + 1) * 64 + bbase + lane) * 1024 + dcol + uglob);
        __hip_atomic_store(hdst, pack, __ATOMIC_RELAXED, __HIP_MEMORY_SCOPE_AGENT);
      }
      if (s < 511) wave_post(gfl + myslot, lane, (unsigned)(s + 1));
    }
  }
  phase_barrier(p.flags, wg, tid, 2u);

  // ---------------- P3: layer1 fwd ((wg&7)<4) | P4: layer1 bwd single step ----------------
  if ((wg & 7) < 4) {
    const int bg = wg & 7;
    const int ug = wg >> 3;
    const int bbase = bg * 16;
    const int uglob = ug * 16 + wv * 4;
    const int colbase = uglob * 4;
    bf16x8 wf[48];                       // register-resident [hh 16 | ih 32]
    #pragma unroll
    for (int kb = 0; kb < 48; ++kb)
      wf[kb] = *(const bf16x8*)(p.Wp1f + (size_t)(colbase + colq) * 1536 + kb * 32 + quad * 8);
    const float bias_col = p.bp[2 * 2048 + colbase + colq];
    f32x4 cc = {0.f, 0.f, 0.f, 0.f};
    if (lane < 16)
      cc = *(const f32x4*)(p.c0 + (size_t)2 * 64 * 512 + (size_t)(bbase + lane) * 512 + uglob);
    unsigned* gfl = p.flags + 1280 + bg * 128;
    const int myslot = ug * 4 + wv;
    for (int t = 0; t < 512; ++t) {
      if (t > 0) group_wait128(gfl, lane, (unsigned)t);
      // x = y0 slab t+1 (L0 output, plain cached; published by barrier 2)
      const __bf16* aX = p.y0 + ((size_t)(t + 1) * 64 + bbase + colq) * 1024 + quad * 8;
      // h = y1f slab t (write-once; plain cached, L2-multicast)
      const __bf16* aH = p.y1f + ((size_t)t * 64 + bbase + colq) * 512 + quad * 8;
      f32x4 acc = {0.f, 0.f, 0.f, 0.f};
      #pragma unroll
      for (int kb = 0; kb < 32; ++kb)
        acc = __builtin_amdgcn_mfma_f32_16x16x32_bf16(*(const bf16x8*)(aX + kb * 32), wf[16 + kb], acc, 0, 0, 0);
      #pragma unroll
      for (int kb = 0; kb < 16; ++kb)
        acc = __builtin_amdgcn_mfma_f32_16x16x32_bf16(*(const bf16x8*)(aH + kb * 32), wf[kb], acc, 0, 0, 0);
      #pragma unroll
      for (int r = 0; r < 4; ++r) ldsw[(quad * 4 + r) * 17 + colq] = acc[r] + bias_col;
      if (lane < 16) {
        unsigned long long pack = 0;
        #pragma unroll
        for (int j = 0; j < 4; ++j) {
          float gi = ldsw[lane * 17 + j * 4 + 0];
          float gf = ldsw[lane * 17 + j * 4 + 1];
          float gg = ldsw[lane * 17 + j * 4 + 2];
          float go = ldsw[lane * 17 + j * 4 + 3];
          float cj = sigm(gf) * cc[j] + sigm(gi) * tanhf(gg);
          cc[j] = cj;
          float h = sigm(go) * tanhf(cj);
          __bf16 hb = (__bf16)h;
          unsigned short hu; __builtin_memcpy(&hu, &hb, 2);
          pack |= (unsigned long long)hu << (16 * j);
        }
        unsigned long long* hdst = (unsigned long long*)
          (p.y1f + ((size_t)(t + 1) * 64 + bbase + lane) * 512 + uglob);
        __hip_atomic_store(hdst, pack, __ATOMIC_RELAXED, __HIP_MEMORY_SCOPE_AGENT);
      }
      if (t < 511) wave_post(gfl + myslot, lane, (unsigned)(t + 1));
    }
  } else {
    const int bg = (wg & 7) - 4;
    const int ug = wg >> 3;
    const int bbase = bg * 16;
    const int uglob = ug * 16 + wv * 4;
    const int colbase = uglob * 4;
    const __bf16* aH = p.h1binit + (size_t)(bbase + colq) * 512 + quad * 8;
    const __bf16* aX = p.y0 + ((size_t)512 * 64 + bbase + colq) * 1024 + quad * 8;
    const __bf16* wrow = p.Wp1b + (size_t)(colbase + colq) * 1536;
    f32x4 acc = {0.f, 0.f, 0.f, 0.f};
    #pragma unroll
    for (int kb = 0; kb < 16; ++kb)
      acc = __builtin_amdgcn_mfma_f32_16x16x32_bf16(*(const bf16x8*)(aH + kb * 32), *(const bf16x8*)(wrow + kb * 32 + quad * 8), acc, 0, 0, 0);
    #pragma unroll
    for (int kb = 0; kb < 32; ++kb)
      acc = __builtin_amdgcn_mfma_f32_16x16x32_bf16(*(const bf16x8*)(aX + kb * 32), *(const bf16x8*)(wrow + (16 + kb) * 32 + quad * 8), acc, 0, 0, 0);
    const float bias_col = p.bp[3 * 2048 + colbase + colq];
    #pragma unroll
    for (int r = 0; r < 4; ++r) ldsw[(quad * 4 + r) * 17 + colq] = acc[r] + bias_col;
    if (lane < 16) {
      f32x4 cc = *(const f32x4*)(p.c0 + (size_t)3 * 64 * 512 + (size_t)(bbase + lane) * 512 + uglob);
      unsigned long long pack = 0;
      #pragma unroll
      for (int j = 0; j < 4; ++j) {
        float gi = ldsw[lane * 17 + j * 4 + 0];
        float gf = ldsw[lane * 17 + j * 4 + 1];
        float gg = ldsw[lane * 17 + j * 4 + 2];
        float go = ldsw[lane * 17 + j * 4 + 3];
        float cj = sigm(gf) * cc[j] + sigm(gi) * tanhf(gg);
        float h = sigm(go) * tanhf(cj);
        __bf16 hb = (__bf16)h;
        unsigned short hu; __builtin_memcpy(&hu, &hb, 2);
        pack |= (unsigned long long)hu << (16 * j);
      }
      unsigned long long* hdst = (unsigned long long*)
        (p.h1bout + (size_t)(bbase + lane) * 512 + uglob);
      __hip_atomic_store(hdst, pack, __ATOMIC_RELAXED, __HIP_MEMORY_SCOPE_AGENT);
    }
  }
  phase_barrier(p.flags, wg, tid, 3u);

  // ---------------- FC: out[b][o] = fc_b[o] + last[b,:] . fc_w[o,:] ----------------
  if (wg < 8) {
    const int b = wg * 8 + (tid >> 5);
    const int o = (tid >> 2) & 7;
    const int ks = tid & 3;
    const int k0 = ks * 256;
    const __bf16* l1 = p.y1f + ((size_t)512 * 64 + b) * 512;   // h1f(t=511) = slab 512
    const __bf16* l2 = p.h1bout + (size_t)b * 512;             // h1b(t=511)
    const __bf16* hsrc = (ks < 2) ? (l1 + k0) : (l2 + k0 - 512);
    const float* w = p.fc_w + (size_t)o * 1024 + k0;
    float acc = 0.f;
    for (int k = 0; k < 256; ++k) acc += (float)hsrc[k] * w[k];
    acc += __shfl_down(acc, 2, 4);
    acc += __shfl_down(acc, 1, 4);
    if (ks == 0) p.out[b * 8 + o] = acc + p.fc_b[o];
  }
}

extern "C" void kernel_launch(void* const* d_in, const int* in_sizes, int n_in,
                              void* d_out, int out_size, void* d_ws, size_t ws_size,
                              hipStream_t stream) {
  char* ws = (char*)d_ws;
  Params p;
  p.input_seq = (const float*)d_in[0];
  p.h0 = (const float*)d_in[1];
  p.c0 = (const float*)d_in[2];
  p.w_ih_0f = (const float*)d_in[3];  p.w_hh_0f = (const float*)d_in[4];  p.b_0f = (const float*)d_in[5];
  p.w_ih_0b = (const float*)d_in[6];  p.w_hh_0b = (const float*)d_in[7];  p.b_0b = (const float*)d_in[8];
  p.w_ih_1f = (const float*)d_in[9];  p.w_hh_1f = (const float*)d_in[10]; p.b_1f = (const float*)d_in[11];
  p.w_ih_1b = (const float*)d_in[12]; p.w_hh_1b = (const float*)d_in[13]; p.b_1b = (const float*)d_in[14];
  p.fc_w = (const float*)d_in[15];    p.fc_b = (const float*)d_in[16];
  p.out = (float*)d_out;

  const size_t FLAG_BYTES = 8192;      // 1792 dense u32 flags (rounded up)
  size_t off = 0;
  p.flags  = (unsigned*)(ws + off); off += FLAG_BYTES;
  p.xT     = (__bf16*)(ws + off);   off += (size_t)512 * 64 * 256 * 2;
  p.Wp0f   = (__bf16*)(ws + off);   off += (size_t)2048 * 768 * 2;
  p.Wp0b   = (__bf16*)(ws + off);   off += (size_t)2048 * 768 * 2;
  p.Wp1f   = (__bf16*)(ws + off);   off += (size_t)2048 * 1536 * 2;
  p.Wp1b   = (__bf16*)(ws + off);   off += (size_t)2048 * 1536 * 2;
  p.y0     = (__bf16*)(ws + off);   off += (size_t)514 * 64 * 1024 * 2;
  p.y1f    = (__bf16*)(ws + off);   off += (size_t)513 * 64 * 512 * 2;
  p.h1binit= (__bf16*)(ws + off);   off += (size_t)64 * 512 * 2;
  p.h1bout = (__bf16*)(ws + off);   off += (size_t)64 * 512 * 2;
  p.bp     = (float*)(ws + off);    off += (size_t)4 * 2048 * 4;
  (void)ws_size; (void)in_sizes; (void)n_in; (void)out_size;

  hipMemsetAsync(d_ws, 0, FLAG_BYTES, stream);   // zero flag slots each call
  lstm_kernel<<<dim3(256), dim3(256), 0, stream>>>(p);
}

// Round 6
// 8447.420 us; speedup vs baseline: 4.1391x; 1.5357x over previous
//
#include <hip/hip_runtime.h>
#include <hip/hip_bf16.h>

// Bidirectional 2-layer LSTM, persistent single-kernel implementation.
// I=256, H=512, L=2, D=2, O=8, B=64, S=512.
//
// Round 6: sync-protocol rebuild (r5 showed a fixed ~15us/hop cost; FETCH
// collapse 6.5GB->212MB left time unchanged => sync queueing, not data).
//  - Per-(group,step) u32 counter, 64B-strided. Producer WG: sc1 h stores ->
//    vmcnt(0) (via barrier) -> ONE posted atomicAdd (no return, no ack).
//  - Consumer WG: tid0 polls ONE line until ==32, __syncthreads releases.
//    Pollers: 1536 waves -> 384 threads; flag lines: ~112 -> 12.
//  - h data path unchanged from r5: producer u64 sc1 stores to IF; consumer
//    plain cached loads on write-once slabs (L2 multicast within the XCD).
//  - Heavy fences (wbl2/inv) only at the 3 phase barriers.

typedef __attribute__((ext_vector_type(8))) __bf16 bf16x8;
typedef __attribute__((ext_vector_type(4))) float f32x4;

struct Params {
  const float *input_seq, *h0, *c0;
  const float *w_ih_0f, *w_hh_0f, *b_0f;
  const float *w_ih_0b, *w_hh_0b, *b_0b;
  const float *w_ih_1f, *w_hh_1f, *b_1f;
  const float *w_ih_1b, *w_hh_1b, *b_1b;
  const float *fc_w, *fc_b;
  float* out;
  unsigned* flags;        // [0,256): phase-barrier slots
  unsigned* cnt;          // [12][512] u32 counters, 64B stride (16 u32)
  __bf16* xT;             // [512][64][256]  time-major bf16 input
  __bf16* Wp0f; __bf16* Wp0b;   // [2048 perm rows][768 = 512 hh | 256 ih]
  __bf16* Wp1f; __bf16* Wp1b;   // [2048 perm rows][1536 = 512 hh | 1024 ih]
  __bf16* y0;             // [514][64][1024]; slab s = t+1; slab0/513 = inits (write-once)
  __bf16* y1f;            // [513][64][512]; slab t+1 = h1f(t); slab0 = h0[2] init (write-once)
  __bf16* h1binit;        // [64][512]
  __bf16* h1bout;         // [64][512]
  float* bp;              // [4][2048] permuted biases (0f,0b,1f,1b)
};

__device__ __forceinline__ float sigm(float x) { return 1.f / (1.f + __expf(-x)); }

// Phase barrier (3 uses): publishes plain cached writes across XCDs.
__device__ __forceinline__ void phase_barrier(unsigned* pf, int wg, int tid, unsigned phase) {
  __syncthreads();
  if (tid == 0) {
    __builtin_amdgcn_fence(__ATOMIC_RELEASE, "agent");
    __hip_atomic_store(pf + wg, phase, __ATOMIC_RELAXED, __HIP_MEMORY_SCOPE_AGENT);
  }
  bool ok;
  do {
    unsigned v = __hip_atomic_load(pf + tid, __ATOMIC_RELAXED, __HIP_MEMORY_SCOPE_AGENT);
    ok = v >= phase;
    if (!ok) __builtin_amdgcn_s_sleep(8);
  } while (!__syncthreads_and(ok));
  __builtin_amdgcn_fence(__ATOMIC_ACQUIRE, "agent");
}

// Single-thread poll of one counter line (sc1 load bypasses stale L2).
__device__ __forceinline__ void poll_cnt(const unsigned* c, unsigned target) {
  while (__hip_atomic_load(c, __ATOMIC_RELAXED, __HIP_MEMORY_SCOPE_AGENT) < target)
    __builtin_amdgcn_s_sleep(1);
}

__global__ __launch_bounds__(256, 2) void lstm_kernel(Params p) {
  const int tid  = threadIdx.x;
  const int wg   = blockIdx.x;
  const unsigned gtid = wg * 256 + tid;
  const int lane = tid & 63;
  const int wv   = tid >> 6;          // wave 0..3
  const int colq = lane & 15;         // A-operand batch row m / B-operand gate col n
  const int quad = lane >> 4;         // k-subblock selector

  __shared__ float lds[4][272];       // stride 17
  float* ldsw = lds[wv];              // wave-private slab

  // ---------------- prologue: pack/permute/convert ----------------
  { // xT[t][b][:] = bf16(input_seq[b][t][:])
    int row = gtid >> 1, half = gtid & 1;
    int t = row >> 6, b = row & 63;
    const float* src = p.input_seq + ((size_t)b * 512 + t) * 256 + half * 128;
    __bf16* dst = p.xT + (size_t)row * 256 + half * 128;
    for (int i = 0; i < 128; i += 8) {
      bf16x8 v;
      #pragma unroll
      for (int j = 0; j < 8; ++j) v[j] = (__bf16)src[i + j];
      *(bf16x8*)(dst + i) = v;
    }
  }
  // Wp0{f,b}: [2048][768]; perm row rr: u=rr>>2,g=rr&3, orig row R=g*512+u
  for (unsigned task = gtid; task < 2u * 2048 * 6; task += 65536) {
    unsigned dir = task / (2048 * 6);
    unsigned rr = (task / 6) % 2048;
    unsigned ch = task % 6;
    unsigned R = (rr & 3) * 512 + (rr >> 2);
    const float* wih = dir ? p.w_ih_0b : p.w_ih_0f;
    const float* whh = dir ? p.w_hh_0b : p.w_hh_0f;
    __bf16* dst = (dir ? p.Wp0b : p.Wp0f) + (size_t)rr * 768;
    const float* src; unsigned kd;
    if (ch < 4) { src = whh + (size_t)R * 512 + ch * 128;        kd = ch * 128; }
    else        { src = wih + (size_t)R * 256 + (ch - 4) * 128;  kd = 512 + (ch - 4) * 128; }
    for (int i = 0; i < 128; i += 8) {
      bf16x8 v;
      #pragma unroll
      for (int j = 0; j < 8; ++j) v[j] = (__bf16)src[i + j];
      *(bf16x8*)(dst + kd + i) = v;
    }
  }
  // Wp1{f,b}: [2048][1536]
  for (unsigned task = gtid; task < 2u * 2048 * 12; task += 65536) {
    unsigned dir = task / (2048 * 12);
    unsigned rr = (task / 12) % 2048;
    unsigned ch = task % 12;
    unsigned R = (rr & 3) * 512 + (rr >> 2);
    const float* wih = dir ? p.w_ih_1b : p.w_ih_1f;
    const float* whh = dir ? p.w_hh_1b : p.w_hh_1f;
    __bf16* dst = (dir ? p.Wp1b : p.Wp1f) + (size_t)rr * 1536;
    const float* src; unsigned kd;
    if (ch < 4) { src = whh + (size_t)R * 512 + ch * 128;         kd = ch * 128; }
    else        { src = wih + (size_t)R * 1024 + (ch - 4) * 128;  kd = 512 + (ch - 4) * 128; }
    for (int i = 0; i < 128; i += 8) {
      bf16x8 v;
      #pragma unroll
      for (int j = 0; j < 8; ++j) v[j] = (__bf16)src[i + j];
      *(bf16x8*)(dst + kd + i) = v;
    }
  }
  // permuted biases
  if (gtid < 4u * 2048) {
    unsigned arr = gtid >> 11, rr = gtid & 2047;
    unsigned R = (rr & 3) * 512 + (rr >> 2);
    const float* src = arr == 0 ? p.b_0f : arr == 1 ? p.b_0b : arr == 2 ? p.b_1f : p.b_1b;
    p.bp[arr * 2048 + rr] = src[R];
  }
  // h inits (bf16): y0 slab0 lo=h0[0]; y0 slab513 hi=h0[1]; y1f slab0=h0[2]; h1binit=h0[3]
  if (gtid < 4u * 4096) {
    unsigned dl = gtid >> 12;
    unsigned e = (gtid & 4095) * 8;
    unsigned b = e >> 9, u = e & 511;
    const float* src = p.h0 + (size_t)dl * 64 * 512 + (size_t)b * 512 + u;
    __bf16* dst;
    if (dl == 0)      dst = p.y0 + ((size_t)0 * 64 + b) * 1024 + u;
    else if (dl == 1) dst = p.y0 + ((size_t)513 * 64 + b) * 1024 + 512 + u;
    else if (dl == 2) dst = p.y1f + ((size_t)0 * 64 + b) * 512 + u;
    else              dst = p.h1binit + (size_t)b * 512 + u;
    bf16x8 v;
    #pragma unroll
    for (int j = 0; j < 8; ++j) v[j] = (__bf16)src[j];
    *(bf16x8*)dst = v;
  }

  phase_barrier(p.flags, wg, tid, 1u);

  // ---------------- P1: layer0 recurrence ----------------
  // group g = wg & 7 (fwd: 0..3, bwd: 4..7; bg = g & 3); ug = wg >> 3.
  {
    const int g = wg & 7;
    const bool fwd = g < 4;
    const int bg = g & 3;
    const int ug = wg >> 3;
    const int bbase = bg * 16;
    const int uglob = ug * 16 + wv * 4;  // this wave: 4 hidden units
    const int colbase = uglob * 4;       // 16 permuted gate cols
    const __bf16* Wp = fwd ? p.Wp0f : p.Wp0b;
    bf16x8 wf[24];
    #pragma unroll
    for (int kb = 0; kb < 24; ++kb)
      wf[kb] = *(const bf16x8*)(Wp + (size_t)(colbase + colq) * 768 + kb * 32 + quad * 8);
    const float bias_col = p.bp[(fwd ? 0 : 1) * 2048 + colbase + colq];
    f32x4 cc = {0.f, 0.f, 0.f, 0.f};     // lanes<16: c for 4 units of batch row (bbase+lane)
    if (lane < 16)
      cc = *(const f32x4*)(p.c0 + (size_t)(fwd ? 0 : 1) * 64 * 512 + (size_t)(bbase + lane) * 512 + uglob);
    const int dcol = fwd ? 0 : 512;
    unsigned* cbase = p.cnt + (size_t)g * 512 * 16;
    for (int s = 0; s < 512; ++s) {
      const int t = fwd ? s : 511 - s;
      const int slabA = fwd ? t : t + 2;   // h(t-1) at slab t; h(t+1) at slab t+2
      // prefetch x fragments (fly during the poll)
      const __bf16* aX = p.xT + ((size_t)t * 64 + bbase + colq) * 256 + quad * 8;
      bf16x8 xf[8];
      #pragma unroll
      for (int kb = 0; kb < 8; ++kb) xf[kb] = *(const bf16x8*)(aX + kb * 32);
      if (s > 0) {
        if (tid == 0) poll_cnt(cbase + (size_t)s * 16, 32u);
        __syncthreads();                  // release all 4 waves
      }
      // h fragments: plain cached (write-once slab; first touch misses to IF,
      // then L2 multicast within the group's XCD)
      const __bf16* aH = p.y0 + ((size_t)slabA * 64 + bbase + colq) * 1024 + dcol + quad * 8;
      f32x4 acc = {0.f, 0.f, 0.f, 0.f};
      #pragma unroll
      for (int kb = 0; kb < 8; ++kb)
        acc = __builtin_amdgcn_mfma_f32_16x16x32_bf16(xf[kb], wf[16 + kb], acc, 0, 0, 0);
      #pragma unroll
      for (int kb = 0; kb < 16; ++kb)
        acc = __builtin_amdgcn_mfma_f32_16x16x32_bf16(*(const bf16x8*)(aH + kb * 32), wf[kb], acc, 0, 0, 0);
      #pragma unroll
      for (int r = 0; r < 4; ++r) ldsw[(quad * 4 + r) * 17 + colq] = acc[r] + bias_col;
      if (lane < 16) {                   // batch row bbase+lane, 4 units
        unsigned long long pack = 0;
        #pragma unroll
        for (int j = 0; j < 4; ++j) {
          float gi = ldsw[lane * 17 + j * 4 + 0];
          float gf = ldsw[lane * 17 + j * 4 + 1];
          float gg = ldsw[lane * 17 + j * 4 + 2];
          float go = ldsw[lane * 17 + j * 4 + 3];
          float cj = sigm(gf) * cc[j] + sigm(gi) * tanhf(gg);
          cc[j] = cj;
          float h = sigm(go) * tanhf(cj);
          __bf16 hb = (__bf16)h;
          unsigned short hu; __builtin_memcpy(&hu, &hb, 2);
          pack |= (unsigned long long)hu << (16 * j);
        }
        unsigned long long* hdst = (unsigned long long*)
          (p.y0 + ((size_t)(t + 1) * 64 + bbase + lane) * 1024 + dcol + uglob);
        __hip_atomic_store(hdst, pack, __ATOMIC_RELAXED, __HIP_MEMORY_SCOPE_AGENT);
      }
      if (s < 511) {
        asm volatile("s_waitcnt vmcnt(0)" ::: "memory");  // own sc1 stores at IF
        __syncthreads();                                  // all 4 waves drained
        if (tid == 0)                                     // one posted add per WG
          (void)__hip_atomic_fetch_add(cbase + (size_t)(s + 1) * 16, 1u,
                                       __ATOMIC_RELAXED, __HIP_MEMORY_SCOPE_AGENT);
      }
    }
  }
  phase_barrier(p.flags, wg, tid, 2u);

  // ---------------- P3: layer1 fwd ((wg&7)<4) | P4: layer1 bwd single step ----------------
  if ((wg & 7) < 4) {
    const int bg = wg & 7;
    const int ug = wg >> 3;
    const int bbase = bg * 16;
    const int uglob = ug * 16 + wv * 4;
    const int colbase = uglob * 4;
    bf16x8 wf[48];                       // [hh 16 | ih 32] frags
    #pragma unroll
    for (int kb = 0; kb < 48; ++kb)
      wf[kb] = *(const bf16x8*)(p.Wp1f + (size_t)(colbase + colq) * 1536 + kb * 32 + quad * 8);
    const float bias_col = p.bp[2 * 2048 + colbase + colq];
    f32x4 cc = {0.f, 0.f, 0.f, 0.f};
    if (lane < 16)
      cc = *(const f32x4*)(p.c0 + (size_t)2 * 64 * 512 + (size_t)(bbase + lane) * 512 + uglob);
    unsigned* cbase = p.cnt + (size_t)(8 + bg) * 512 * 16;
    for (int t = 0; t < 512; ++t) {
      // prefetch x = y0 slab t+1 (available since barrier 2; fly during poll)
      const __bf16* aX = p.y0 + ((size_t)(t + 1) * 64 + bbase + colq) * 1024 + quad * 8;
      bf16x8 xf[32];
      #pragma unroll
      for (int kb = 0; kb < 32; ++kb) xf[kb] = *(const bf16x8*)(aX + kb * 32);
      if (t > 0) {
        if (tid == 0) poll_cnt(cbase + (size_t)t * 16, 32u);
        __syncthreads();
      }
      // h = y1f slab t (write-once; plain cached, L2-multicast)
      const __bf16* aH = p.y1f + ((size_t)t * 64 + bbase + colq) * 512 + quad * 8;
      f32x4 acc = {0.f, 0.f, 0.f, 0.f};
      #pragma unroll
      for (int kb = 0; kb < 32; ++kb)
        acc = __builtin_amdgcn_mfma_f32_16x16x32_bf16(xf[kb], wf[16 + kb], acc, 0, 0, 0);
      #pragma unroll
      for (int kb = 0; kb < 16; ++kb)
        acc = __builtin_amdgcn_mfma_f32_16x16x32_bf16(*(const bf16x8*)(aH + kb * 32), wf[kb], acc, 0, 0, 0);
      #pragma unroll
      for (int r = 0; r < 4; ++r) ldsw[(quad * 4 + r) * 17 + colq] = acc[r] + bias_col;
      if (lane < 16) {
        unsigned long long pack = 0;
        #pragma unroll
        for (int j = 0; j < 4; ++j) {
          float gi = ldsw[lane * 17 + j * 4 + 0];
          float gf = ldsw[lane * 17 + j * 4 + 1];
          float gg = ldsw[lane * 17 + j * 4 + 2];
          float go = ldsw[lane * 17 + j * 4 + 3];
          float cj = sigm(gf) * cc[j] + sigm(gi) * tanhf(gg);
          cc[j] = cj;
          float h = sigm(go) * tanhf(cj);
          __bf16 hb = (__bf16)h;
          unsigned short hu; __builtin_memcpy(&hu, &hb, 2);
          pack |= (unsigned long long)hu << (16 * j);
        }
        unsigned long long* hdst = (unsigned long long*)
          (p.y1f + ((size_t)(t + 1) * 64 + bbase + lane) * 512 + uglob);
        __hip_atomic_store(hdst, pack, __ATOMIC_RELAXED, __HIP_MEMORY_SCOPE_AGENT);
      }
      if (t < 511) {
        asm volatile("s_waitcnt vmcnt(0)" ::: "memory");
        __syncthreads();
        if (tid == 0)
          (void)__hip_atomic_fetch_add(cbase + (size_t)(t + 1) * 16, 1u,
                                       __ATOMIC_RELAXED, __HIP_MEMORY_SCOPE_AGENT);
      }
    }
  } else {
    const int bg = (wg & 7) - 4;
    const int ug = wg >> 3;
    const int bbase = bg * 16;
    const int uglob = ug * 16 + wv * 4;
    const int colbase = uglob * 4;
    const __bf16* aH = p.h1binit + (size_t)(bbase + colq) * 512 + quad * 8;
    const __bf16* aX = p.y0 + ((size_t)512 * 64 + bbase + colq) * 1024 + quad * 8;
    const __bf16* wrow = p.Wp1b + (size_t)(colbase + colq) * 1536;
    f32x4 acc = {0.f, 0.f, 0.f, 0.f};
    #pragma unroll
    for (int kb = 0; kb < 16; ++kb)
      acc = __builtin_amdgcn_mfma_f32_16x16x32_bf16(*(const bf16x8*)(aH + kb * 32), *(const bf16x8*)(wrow + kb * 32 + quad * 8), acc, 0, 0, 0);
    #pragma unroll
    for (int kb = 0; kb < 32; ++kb)
      acc = __builtin_amdgcn_mfma_f32_16x16x32_bf16(*(const bf16x8*)(aX + kb * 32), *(const bf16x8*)(wrow + (16 + kb) * 32 + quad * 8), acc, 0, 0, 0);
    const float bias_col = p.bp[3 * 2048 + colbase + colq];
    #pragma unroll
    for (int r = 0; r < 4; ++r) ldsw[(quad * 4 + r) * 17 + colq] = acc[r] + bias_col;
    if (lane < 16) {
      f32x4 cc = *(const f32x4*)(p.c0 + (size_t)3 * 64 * 512 + (size_t)(bbase + lane) * 512 + uglob);
      unsigned long long pack = 0;
      #pragma unroll
      for (int j = 0; j < 4; ++j) {
        float gi = ldsw[lane * 17 + j * 4 + 0];
        float gf = ldsw[lane * 17 + j * 4 + 1];
        float gg = ldsw[lane * 17 + j * 4 + 2];
        float go = ldsw[lane * 17 + j * 4 + 3];
        float cj = sigm(gf) * cc[j] + sigm(gi) * tanhf(gg);
        float h = sigm(go) * tanhf(cj);
        __bf16 hb = (__bf16)h;
        unsigned short hu; __builtin_memcpy(&hu, &hb, 2);
        pack |= (unsigned long long)hu << (16 * j);
      }
      unsigned long long* hdst = (unsigned long long*)
        (p.h1bout + (size_t)(bbase + lane) * 512 + uglob);
      __hip_atomic_store(hdst, pack, __ATOMIC_RELAXED, __HIP_MEMORY_SCOPE_AGENT);
    }
  }
  phase_barrier(p.flags, wg, tid, 3u);

  // ---------------- FC: out[b][o] = fc_b[o] + last[b,:] . fc_w[o,:] ----------------
  if (wg < 8) {
    const int b = wg * 8 + (tid >> 5);
    const int o = (tid >> 2) & 7;
    const int ks = tid & 3;
    const int k0 = ks * 256;
    const __bf16* l1 = p.y1f + ((size_t)512 * 64 + b) * 512;   // h1f(t=511) = slab 512
    const __bf16* l2 = p.h1bout + (size_t)b * 512;             // h1b(t=511)
    const __bf16* hsrc = (ks < 2) ? (l1 + k0) : (l2 + k0 - 512);
    const float* w = p.fc_w + (size_t)o * 1024 + k0;
    float acc = 0.f;
    for (int k = 0; k < 256; ++k) acc += (float)hsrc[k] * w[k];
    acc += __shfl_down(acc, 2, 4);
    acc += __shfl_down(acc, 1, 4);
    if (ks == 0) p.out[b * 8 + o] = acc + p.fc_b[o];
  }
}

extern "C" void kernel_launch(void* const* d_in, const int* in_sizes, int n_in,
                              void* d_out, int out_size, void* d_ws, size_t ws_size,
                              hipStream_t stream) {
  char* ws = (char*)d_ws;
  Params p;
  p.input_seq = (const float*)d_in[0];
  p.h0 = (const float*)d_in[1];
  p.c0 = (const float*)d_in[2];
  p.w_ih_0f = (const float*)d_in[3];  p.w_hh_0f = (const float*)d_in[4];  p.b_0f = (const float*)d_in[5];
  p.w_ih_0b = (const float*)d_in[6];  p.w_hh_0b = (const float*)d_in[7];  p.b_0b = (const float*)d_in[8];
  p.w_ih_1f = (const float*)d_in[9];  p.w_hh_1f = (const float*)d_in[10]; p.b_1f = (const float*)d_in[11];
  p.w_ih_1b = (const float*)d_in[12]; p.w_hh_1b = (const float*)d_in[13]; p.b_1b = (const float*)d_in[14];
  p.fc_w = (const float*)d_in[15];    p.fc_b = (const float*)d_in[16];
  p.out = (float*)d_out;

  const size_t CNT_BYTES = (size_t)12 * 512 * 64;   // 393216
  const size_t SYNC_BYTES = 4096 + CNT_BYTES;
  size_t off = 0;
  p.flags  = (unsigned*)(ws + off); off += 4096;
  p.cnt    = (unsigned*)(ws + off); off += CNT_BYTES;
  p.xT     = (__bf16*)(ws + off);   off += (size_t)512 * 64 * 256 * 2;
  p.Wp0f   = (__bf16*)(ws + off);   off += (size_t)2048 * 768 * 2;
  p.Wp0b   = (__bf16*)(ws + off);   off += (size_t)2048 * 768 * 2;
  p.Wp1f   = (__bf16*)(ws + off);   off += (size_t)2048 * 1536 * 2;
  p.Wp1b   = (__bf16*)(ws + off);   off += (size_t)2048 * 1536 * 2;
  p.y0     = (__bf16*)(ws + off);   off += (size_t)514 * 64 * 1024 * 2;
  p.y1f    = (__bf16*)(ws + off);   off += (size_t)513 * 64 * 512 * 2;
  p.h1binit= (__bf16*)(ws + off);   off += (size_t)64 * 512 * 2;
  p.h1bout = (__bf16*)(ws + off);   off += (size_t)64 * 512 * 2;
  p.bp     = (float*)(ws + off);    off += (size_t)4 * 2048 * 4;
  (void)ws_size; (void)in_sizes; (void)n_in; (void)out_size;

  hipMemsetAsync(d_ws, 0, SYNC_BYTES, stream);   // zero phase flags + counters
  lstm_kernel<<<dim3(256), dim3(256), 0, stream>>>(p);
}

// Round 7
// 7866.489 us; speedup vs baseline: 4.4448x; 1.0738x over previous
//
#include <hip/hip_runtime.h>
#include <hip/hip_bf16.h>

// Bidirectional 2-layer LSTM, persistent single-kernel implementation.
// I=256, H=512, L=2, D=2, O=8, B=64, S=512.
//
// Round 7: kill the same-line serialization at the IF slice (r1/r5/r6 all
// funneled the per-step signal through one or few 64-B lines; IF processes
// same-line RMWs/stores serially ~200-270ns each => 6-32us hops).
//  - Per-producer monotonic flag, ONE 64-B line per producer WG (32 lines
//    per group): stores are fully parallel, single-writer per line.
//  - Consumer: wave 0 lanes 0..31 poll the 32 lines in one gather round
//    trip; ballot; __syncthreads releases the WG.
//  - 64-lane pointwise (was 16 lanes x 4 serial unit-chains): LDS stride 20,
//    ds_read_b128 gate fetch, one transcendental chain per lane, shfl pack
//    4x bf16 -> u64 sc1 store.
//  - h transport unchanged from r5/r6: producer u64 sc1 stores -> IF;
//    consumer plain cached loads on write-once slabs (L2 multicast).

typedef __attribute__((ext_vector_type(8))) __bf16 bf16x8;
typedef __attribute__((ext_vector_type(4))) float f32x4;

struct Params {
  const float *input_seq, *h0, *c0;
  const float *w_ih_0f, *w_hh_0f, *b_0f;
  const float *w_ih_0b, *w_hh_0b, *b_0b;
  const float *w_ih_1f, *w_hh_1f, *b_1f;
  const float *w_ih_1b, *w_hh_1b, *b_1b;
  const float *fc_w, *fc_b;
  float* out;
  unsigned* flags;        // [0,256): phase-barrier slots
  unsigned* stepf;        // [12 groups][32 producers][16 u32] monotonic flags, 64B/producer
  __bf16* xT;             // [512][64][256]  time-major bf16 input
  __bf16* Wp0f; __bf16* Wp0b;   // [2048 perm rows][768 = 512 hh | 256 ih]
  __bf16* Wp1f; __bf16* Wp1b;   // [2048 perm rows][1536 = 512 hh | 1024 ih]
  __bf16* y0;             // [514][64][1024]; slab s = t+1; slab0/513 = inits (write-once)
  __bf16* y1f;            // [513][64][512]; slab t+1 = h1f(t); slab0 = h0[2] init (write-once)
  __bf16* h1binit;        // [64][512]
  __bf16* h1bout;         // [64][512]
  float* bp;              // [4][2048] permuted biases (0f,0b,1f,1b)
};

__device__ __forceinline__ float sigm(float x) { return 1.f / (1.f + __expf(-x)); }

// Phase barrier (3 uses): publishes plain cached writes across XCDs.
__device__ __forceinline__ void phase_barrier(unsigned* pf, int wg, int tid, unsigned phase) {
  __syncthreads();
  if (tid == 0) {
    __builtin_amdgcn_fence(__ATOMIC_RELEASE, "agent");
    __hip_atomic_store(pf + wg, phase, __ATOMIC_RELAXED, __HIP_MEMORY_SCOPE_AGENT);
  }
  bool ok;
  do {
    unsigned v = __hip_atomic_load(pf + tid, __ATOMIC_RELAXED, __HIP_MEMORY_SCOPE_AGENT);
    ok = v >= phase;
    if (!ok) __builtin_amdgcn_s_sleep(8);
  } while (!__syncthreads_and(ok));
  __builtin_amdgcn_fence(__ATOMIC_ACQUIRE, "agent");
}

// Wave 0: lanes 0..31 poll 32 producer flag lines (64B stride) in parallel.
__device__ __forceinline__ void group_wait32(const unsigned* base, int lane, unsigned need) {
  for (;;) {
    bool ok = true;
    if (lane < 32)
      ok = __hip_atomic_load(base + (size_t)lane * 16, __ATOMIC_RELAXED,
                             __HIP_MEMORY_SCOPE_AGENT) >= need;
    if (__ballot(ok) == ~0ull) break;
    __builtin_amdgcn_s_sleep(1);
  }
  asm volatile("" ::: "memory");   // no hoisting of h loads above the poll
}

// Pointwise for one step: 64 lanes, one hidden unit each (b=lane>>2, u=lane&3).
// Reads gates {i,f,g,o} as one f32x4 from LDS (stride 20), updates c, packs
// 4 units' h via shfl, lanes with (lane&3)==0 store one u64 sc1.
__device__ __forceinline__ void pointwise_store(float* ldsw, int lane, float& c,
                                                __bf16* rowbase_u0 /* row bbase+(lane>>2), col uglob */) {
  f32x4 g4 = *(const f32x4*)(ldsw + (lane >> 2) * 20 + (lane & 3) * 4);
  float cj = sigm(g4[1]) * c + sigm(g4[0]) * tanhf(g4[2]);
  c = cj;
  float h = sigm(g4[3]) * tanhf(cj);
  __bf16 hb = (__bf16)h;
  unsigned short hu; __builtin_memcpy(&hu, &hb, 2);
  unsigned v0 = (unsigned)hu | (__shfl_down((unsigned)hu, 1, 4) << 16);
  unsigned long long pk = (unsigned long long)v0 |
                          ((unsigned long long)__shfl_down(v0, 2, 4) << 32);
  if ((lane & 3) == 0)
    __hip_atomic_store((unsigned long long*)rowbase_u0, pk,
                       __ATOMIC_RELAXED, __HIP_MEMORY_SCOPE_AGENT);
}

__global__ __launch_bounds__(256, 2) void lstm_kernel(Params p) {
  const int tid  = threadIdx.x;
  const int wg   = blockIdx.x;
  const unsigned gtid = wg * 256 + tid;
  const int lane = tid & 63;
  const int wv   = tid >> 6;          // wave 0..3
  const int colq = lane & 15;         // A-operand batch row m / B-operand gate col n
  const int quad = lane >> 4;         // k-subblock selector

  __shared__ float lds[4][320];       // stride 20: aligned f32x4, ~2-way banks
  float* ldsw = lds[wv];              // wave-private slab

  // ---------------- prologue: pack/permute/convert ----------------
  { // xT[t][b][:] = bf16(input_seq[b][t][:])
    int row = gtid >> 1, half = gtid & 1;
    int t = row >> 6, b = row & 63;
    const float* src = p.input_seq + ((size_t)b * 512 + t) * 256 + half * 128;
    __bf16* dst = p.xT + (size_t)row * 256 + half * 128;
    for (int i = 0; i < 128; i += 8) {
      bf16x8 v;
      #pragma unroll
      for (int j = 0; j < 8; ++j) v[j] = (__bf16)src[i + j];
      *(bf16x8*)(dst + i) = v;
    }
  }
  // Wp0{f,b}: [2048][768]; perm row rr: u=rr>>2,g=rr&3, orig row R=g*512+u
  for (unsigned task = gtid; task < 2u * 2048 * 6; task += 65536) {
    unsigned dir = task / (2048 * 6);
    unsigned rr = (task / 6) % 2048;
    unsigned ch = task % 6;
    unsigned R = (rr & 3) * 512 + (rr >> 2);
    const float* wih = dir ? p.w_ih_0b : p.w_ih_0f;
    const float* whh = dir ? p.w_hh_0b : p.w_hh_0f;
    __bf16* dst = (dir ? p.Wp0b : p.Wp0f) + (size_t)rr * 768;
    const float* src; unsigned kd;
    if (ch < 4) { src = whh + (size_t)R * 512 + ch * 128;        kd = ch * 128; }
    else        { src = wih + (size_t)R * 256 + (ch - 4) * 128;  kd = 512 + (ch - 4) * 128; }
    for (int i = 0; i < 128; i += 8) {
      bf16x8 v;
      #pragma unroll
      for (int j = 0; j < 8; ++j) v[j] = (__bf16)src[i + j];
      *(bf16x8*)(dst + kd + i) = v;
    }
  }
  // Wp1{f,b}: [2048][1536]
  for (unsigned task = gtid; task < 2u * 2048 * 12; task += 65536) {
    unsigned dir = task / (2048 * 12);
    unsigned rr = (task / 12) % 2048;
    unsigned ch = task % 12;
    unsigned R = (rr & 3) * 512 + (rr >> 2);
    const float* wih = dir ? p.w_ih_1b : p.w_ih_1f;
    const float* whh = dir ? p.w_hh_1b : p.w_hh_1f;
    __bf16* dst = (dir ? p.Wp1b : p.Wp1f) + (size_t)rr * 1536;
    const float* src; unsigned kd;
    if (ch < 4) { src = whh + (size_t)R * 512 + ch * 128;         kd = ch * 128; }
    else        { src = wih + (size_t)R * 1024 + (ch - 4) * 128;  kd = 512 + (ch - 4) * 128; }
    for (int i = 0; i < 128; i += 8) {
      bf16x8 v;
      #pragma unroll
      for (int j = 0; j < 8; ++j) v[j] = (__bf16)src[i + j];
      *(bf16x8*)(dst + kd + i) = v;
    }
  }
  // permuted biases
  if (gtid < 4u * 2048) {
    unsigned arr = gtid >> 11, rr = gtid & 2047;
    unsigned R = (rr & 3) * 512 + (rr >> 2);
    const float* src = arr == 0 ? p.b_0f : arr == 1 ? p.b_0b : arr == 2 ? p.b_1f : p.b_1b;
    p.bp[arr * 2048 + rr] = src[R];
  }
  // h inits (bf16): y0 slab0 lo=h0[0]; y0 slab513 hi=h0[1]; y1f slab0=h0[2]; h1binit=h0[3]
  if (gtid < 4u * 4096) {
    unsigned dl = gtid >> 12;
    unsigned e = (gtid & 4095) * 8;
    unsigned b = e >> 9, u = e & 511;
    const float* src = p.h0 + (size_t)dl * 64 * 512 + (size_t)b * 512 + u;
    __bf16* dst;
    if (dl == 0)      dst = p.y0 + ((size_t)0 * 64 + b) * 1024 + u;
    else if (dl == 1) dst = p.y0 + ((size_t)513 * 64 + b) * 1024 + 512 + u;
    else if (dl == 2) dst = p.y1f + ((size_t)0 * 64 + b) * 512 + u;
    else              dst = p.h1binit + (size_t)b * 512 + u;
    bf16x8 v;
    #pragma unroll
    for (int j = 0; j < 8; ++j) v[j] = (__bf16)src[j];
    *(bf16x8*)dst = v;
  }

  phase_barrier(p.flags, wg, tid, 1u);

  // ---------------- P1: layer0 recurrence ----------------
  // group g = wg & 7 (fwd: 0..3, bwd: 4..7; bg = g & 3); ug = wg >> 3.
  {
    const int g = wg & 7;
    const bool fwd = g < 4;
    const int bg = g & 3;
    const int ug = wg >> 3;
    const int bbase = bg * 16;
    const int uglob = ug * 16 + wv * 4;  // this wave: 4 hidden units
    const int colbase = uglob * 4;       // 16 permuted gate cols
    const __bf16* Wp = fwd ? p.Wp0f : p.Wp0b;
    bf16x8 wf[24];
    #pragma unroll
    for (int kb = 0; kb < 24; ++kb)
      wf[kb] = *(const bf16x8*)(Wp + (size_t)(colbase + colq) * 768 + kb * 32 + quad * 8);
    const float bias_col = p.bp[(fwd ? 0 : 1) * 2048 + colbase + colq];
    // per-lane c: batch row bbase+(lane>>2), unit uglob+(lane&3)
    float c = p.c0[(size_t)(fwd ? 0 : 1) * 64 * 512 +
                   (size_t)(bbase + (lane >> 2)) * 512 + uglob + (lane & 3)];
    const int dcol = fwd ? 0 : 512;
    unsigned* gfl = p.stepf + (size_t)g * 32 * 16;
    for (int s = 0; s < 512; ++s) {
      const int t = fwd ? s : 511 - s;
      const int slabA = fwd ? t : t + 2;   // h(t-1) at slab t; h(t+1) at slab t+2
      // prefetch x fragments (fly during the poll)
      const __bf16* aX = p.xT + ((size_t)t * 64 + bbase + colq) * 256 + quad * 8;
      bf16x8 xf[8];
      #pragma unroll
      for (int kb = 0; kb < 8; ++kb) xf[kb] = *(const bf16x8*)(aX + kb * 32);
      if (s > 0) {
        if (wv == 0) group_wait32(gfl, lane, (unsigned)s);
        __syncthreads();                  // release all 4 waves
      }
      // h fragments: plain cached (write-once slab; first touch misses to IF,
      // then L2 multicast within the group's XCD)
      const __bf16* aH = p.y0 + ((size_t)slabA * 64 + bbase + colq) * 1024 + dcol + quad * 8;
      f32x4 acc = {0.f, 0.f, 0.f, 0.f};
      #pragma unroll
      for (int kb = 0; kb < 8; ++kb)
        acc = __builtin_amdgcn_mfma_f32_16x16x32_bf16(xf[kb], wf[16 + kb], acc, 0, 0, 0);
      #pragma unroll
      for (int kb = 0; kb < 16; ++kb)
        acc = __builtin_amdgcn_mfma_f32_16x16x32_bf16(*(const bf16x8*)(aH + kb * 32), wf[kb], acc, 0, 0, 0);
      // acc[r]: batch row quad*4+r, gate col colq -> LDS [batch][gate], stride 20
      #pragma unroll
      for (int r = 0; r < 4; ++r) ldsw[(quad * 4 + r) * 20 + colq] = acc[r] + bias_col;
      pointwise_store(ldsw, lane, c,
        p.y0 + ((size_t)(t + 1) * 64 + bbase + (lane >> 2)) * 1024 + dcol + uglob);
      if (s < 511) {
        asm volatile("s_waitcnt vmcnt(0)" ::: "memory");  // own sc1 stores at IF
        __syncthreads();                                  // all 4 waves drained
        if (tid == 0)                                     // single-writer flag line
          __hip_atomic_store(gfl + (size_t)ug * 16, (unsigned)(s + 1),
                             __ATOMIC_RELAXED, __HIP_MEMORY_SCOPE_AGENT);
      }
    }
  }
  phase_barrier(p.flags, wg, tid, 2u);

  // ---------------- P3: layer1 fwd ((wg&7)<4) | P4: layer1 bwd single step ----------------
  if ((wg & 7) < 4) {
    const int bg = wg & 7;
    const int ug = wg >> 3;
    const int bbase = bg * 16;
    const int uglob = ug * 16 + wv * 4;
    const int colbase = uglob * 4;
    bf16x8 wf[48];                       // [hh 16 | ih 32] frags
    #pragma unroll
    for (int kb = 0; kb < 48; ++kb)
      wf[kb] = *(const bf16x8*)(p.Wp1f + (size_t)(colbase + colq) * 1536 + kb * 32 + quad * 8);
    const float bias_col = p.bp[2 * 2048 + colbase + colq];
    float c = p.c0[(size_t)2 * 64 * 512 +
                   (size_t)(bbase + (lane >> 2)) * 512 + uglob + (lane & 3)];
    unsigned* gfl = p.stepf + (size_t)(8 + bg) * 32 * 16;
    for (int t = 0; t < 512; ++t) {
      // prefetch x = y0 slab t+1 (available since barrier 2; fly during poll)
      const __bf16* aX = p.y0 + ((size_t)(t + 1) * 64 + bbase + colq) * 1024 + quad * 8;
      bf16x8 xf[32];
      #pragma unroll
      for (int kb = 0; kb < 32; ++kb) xf[kb] = *(const bf16x8*)(aX + kb * 32);
      if (t > 0) {
        if (wv == 0) group_wait32(gfl, lane, (unsigned)t);
        __syncthreads();
      }
      // h = y1f slab t (write-once; plain cached, L2-multicast)
      const __bf16* aH = p.y1f + ((size_t)t * 64 + bbase + colq) * 512 + quad * 8;
      f32x4 acc = {0.f, 0.f, 0.f, 0.f};
      #pragma unroll
      for (int kb = 0; kb < 32; ++kb)
        acc = __builtin_amdgcn_mfma_f32_16x16x32_bf16(xf[kb], wf[16 + kb], acc, 0, 0, 0);
      #pragma unroll
      for (int kb = 0; kb < 16; ++kb)
        acc = __builtin_amdgcn_mfma_f32_16x16x32_bf16(*(const bf16x8*)(aH + kb * 32), wf[kb], acc, 0, 0, 0);
      #pragma unroll
      for (int r = 0; r < 4; ++r) ldsw[(quad * 4 + r) * 20 + colq] = acc[r] + bias_col;
      pointwise_store(ldsw, lane, c,
        p.y1f + ((size_t)(t + 1) * 64 + bbase + (lane >> 2)) * 512 + uglob);
      if (t < 511) {
        asm volatile("s_waitcnt vmcnt(0)" ::: "memory");
        __syncthreads();
        if (tid == 0)
          __hip_atomic_store(gfl + (size_t)ug * 16, (unsigned)(t + 1),
                             __ATOMIC_RELAXED, __HIP_MEMORY_SCOPE_AGENT);
      }
    }
  } else {
    const int bg = (wg & 7) - 4;
    const int ug = wg >> 3;
    const int bbase = bg * 16;
    const int uglob = ug * 16 + wv * 4;
    const int colbase = uglob * 4;
    const __bf16* aH = p.h1binit + (size_t)(bbase + colq) * 512 + quad * 8;
    const __bf16* aX = p.y0 + ((size_t)512 * 64 + bbase + colq) * 1024 + quad * 8;
    const __bf16* wrow = p.Wp1b + (size_t)(colbase + colq) * 1536;
    f32x4 acc = {0.f, 0.f, 0.f, 0.f};
    #pragma unroll
    for (int kb = 0; kb < 16; ++kb)
      acc = __builtin_amdgcn_mfma_f32_16x16x32_bf16(*(const bf16x8*)(aH + kb * 32), *(const bf16x8*)(wrow + kb * 32 + quad * 8), acc, 0, 0, 0);
    #pragma unroll
    for (int kb = 0; kb < 32; ++kb)
      acc = __builtin_amdgcn_mfma_f32_16x16x32_bf16(*(const bf16x8*)(aX + kb * 32), *(const bf16x8*)(wrow + (16 + kb) * 32 + quad * 8), acc, 0, 0, 0);
    const float bias_col = p.bp[3 * 2048 + colbase + colq];
    #pragma unroll
    for (int r = 0; r < 4; ++r) ldsw[(quad * 4 + r) * 20 + colq] = acc[r] + bias_col;
    float c = p.c0[(size_t)3 * 64 * 512 +
                   (size_t)(bbase + (lane >> 2)) * 512 + uglob + (lane & 3)];
    pointwise_store(ldsw, lane, c,
      p.h1bout + (size_t)(bbase + (lane >> 2)) * 512 + uglob);
  }
  phase_barrier(p.flags, wg, tid, 3u);

  // ---------------- FC: out[b][o] = fc_b[o] + last[b,:] . fc_w[o,:] ----------------
  if (wg < 8) {
    const int b = wg * 8 + (tid >> 5);
    const int o = (tid >> 2) & 7;
    const int ks = tid & 3;
    const int k0 = ks * 256;
    const __bf16* l1 = p.y1f + ((size_t)512 * 64 + b) * 512;   // h1f(t=511) = slab 512
    const __bf16* l2 = p.h1bout + (size_t)b * 512;             // h1b(t=511)
    const __bf16* hsrc = (ks < 2) ? (l1 + k0) : (l2 + k0 - 512);
    const float* w = p.fc_w + (size_t)o * 1024 + k0;
    float acc = 0.f;
    for (int k = 0; k < 256; ++k) acc += (float)hsrc[k] * w[k];
    acc += __shfl_down(acc, 2, 4);
    acc += __shfl_down(acc, 1, 4);
    if (ks == 0) p.out[b * 8 + o] = acc + p.fc_b[o];
  }
}

extern "C" void kernel_launch(void* const* d_in, const int* in_sizes, int n_in,
                              void* d_out, int out_size, void* d_ws, size_t ws_size,
                              hipStream_t stream) {
  char* ws = (char*)d_ws;
  Params p;
  p.input_seq = (const float*)d_in[0];
  p.h0 = (const float*)d_in[1];
  p.c0 = (const float*)d_in[2];
  p.w_ih_0f = (const float*)d_in[3];  p.w_hh_0f = (const float*)d_in[4];  p.b_0f = (const float*)d_in[5];
  p.w_ih_0b = (const float*)d_in[6];  p.w_hh_0b = (const float*)d_in[7];  p.b_0b = (const float*)d_in[8];
  p.w_ih_1f = (const float*)d_in[9];  p.w_hh_1f = (const float*)d_in[10]; p.b_1f = (const float*)d_in[11];
  p.w_ih_1b = (const float*)d_in[12]; p.w_hh_1b = (const float*)d_in[13]; p.b_1b = (const float*)d_in[14];
  p.fc_w = (const float*)d_in[15];    p.fc_b = (const float*)d_in[16];
  p.out = (float*)d_out;

  const size_t STEPF_BYTES = (size_t)12 * 32 * 64;   // 24576
  const size_t SYNC_BYTES = 4096 + STEPF_BYTES;
  size_t off = 0;
  p.flags  = (unsigned*)(ws + off); off += 4096;
  p.stepf  = (unsigned*)(ws + off); off += STEPF_BYTES;
  p.xT     = (__bf16*)(ws + off);   off += (size_t)512 * 64 * 256 * 2;
  p.Wp0f   = (__bf16*)(ws + off);   off += (size_t)2048 * 768 * 2;
  p.Wp0b   = (__bf16*)(ws + off);   off += (size_t)2048 * 768 * 2;
  p.Wp1f   = (__bf16*)(ws + off);   off += (size_t)2048 * 1536 * 2;
  p.Wp1b   = (__bf16*)(ws + off);   off += (size_t)2048 * 1536 * 2;
  p.y0     = (__bf16*)(ws + off);   off += (size_t)514 * 64 * 1024 * 2;
  p.y1f    = (__bf16*)(ws + off);   off += (size_t)513 * 64 * 512 * 2;
  p.h1binit= (__bf16*)(ws + off);   off += (size_t)64 * 512 * 2;
  p.h1bout = (__bf16*)(ws + off);   off += (size_t)64 * 512 * 2;
  p.bp     = (float*)(ws + off);    off += (size_t)4 * 2048 * 4;
  (void)ws_size; (void)in_sizes; (void)n_in; (void)out_size;

  hipMemsetAsync(d_ws, 0, SYNC_BYTES, stream);   // zero phase flags + step flags
  lstm_kernel<<<dim3(256), dim3(256), 0, stream>>>(p);
}